// Round 4
// baseline (716.000 us; speedup 1.0000x reference)
//
#include <hip/hip_runtime.h>
#include <stdint.h>

#define B_  128
#define C_  512
#define G_  20
#define K2  4608      // C_*9, conv GEMM K
#define FCK 18432     // C_*36, fc GEMM K

typedef unsigned short u16;
typedef unsigned int   u32;
typedef __attribute__((ext_vector_type(8))) short  short8;
typedef __attribute__((ext_vector_type(4))) float  float4v;

__device__ __forceinline__ u16 f2bf(float f) {
  u32 u = __builtin_bit_cast(u32, f);
  u = (u + 0x7fffu + ((u >> 16) & 1u)) >> 16;   // RNE
  return (u16)u;
}

__device__ __forceinline__ void load_lds16(const void* g, void* l) {
  __builtin_amdgcn_global_load_lds(
      (const __attribute__((address_space(1))) void*)(uintptr_t)g,
      (__attribute__((address_space(3))) void*)(uint32_t)(uintptr_t)l,
      16, 0, 0);
}

// ---------------- landmarks -> integer crop positions ----------------
__global__ void k_pos(const float* __restrict__ y, int* __restrict__ cx, int* __restrict__ cy) {
  int b = blockIdx.x * blockDim.x + threadIdx.x;
  if (b >= B_) return;
  const int   I1[10] = {21,18,19,41,38,49,48,51,61,56};
  const int   I2[10] = {22,25,24,46,43,53,54,57,63,58};
  const float CF[10] = {-0.5f, -1.0f/3.0f, 1.0f/3.0f, 1.0f, 0.f,0.f,0.f,0.f,0.f, 0.5f};
  const float* yb = y + b * 136;
  float ruler = fabsf(yb[2*39] - yb[2*42]);
  for (int j = 0; j < 10; ++j) {
    float off = ruler * CF[j];
    float vx1 = yb[2*I1[j]];
    float vy1 = yb[2*I1[j]+1] + off;
    float vx2 = yb[2*I2[j]];
    float vy2 = yb[2*I2[j]+1] + off;
    int px1 = (int)(vx1 * 0.0625f); px1 = min(max(px1,1),12);
    int py1 = (int)(vy1 * 0.0625f); py1 = min(max(py1,1),12);
    int px2 = (int)(vx2 * 0.0625f); px2 = min(max(px2,1),12);
    int py2 = (int)(vy2 * 0.0625f); py2 = min(max(py2,1),12);
    cx[b*20 + 2*j]   = px1;  cx[b*20 + 2*j+1] = px2;
    cy[b*20 + 2*j]   = py1;  cy[b*20 + 2*j+1] = py2;
  }
}

// ------------- conv_w f32 [o][ci][t] -> bf16 Wb[o][t*512+ci] -------------
__global__ void k_convw(const float* __restrict__ w, u16* __restrict__ wb) {
  int tid = blockIdx.x * 256 + threadIdx.x;       // 10240*512 threads
  int o = tid >> 9, ci = tid & 511;
  const float* src = w + (size_t)tid * 9;         // (o*512+ci)*9
  u16* dst = wb + (size_t)o * K2 + ci;
  #pragma unroll
  for (int t = 0; t < 9; ++t) dst[t*512] = f2bf(src[t]);
}

// ------- fc_w f32 [g][i][o:150] -> bf16 Wfcb[g][o:160(pad0)][i] -------
// LDS-transposed: coalesced panel read, coalesced short8 writes.
__global__ void __launch_bounds__(256) k_fcw(const float* __restrict__ fw, u16* __restrict__ wfcb) {
  __shared__ u16 tile[128 * 161];                 // [il][o], stride 161 (conflict pad)
  int chunk = blockIdx.x;                         // 0..143 (FCK/128)
  int g     = blockIdx.y;
  int tid   = threadIdx.x;
  const float* src = fw + (size_t)g * FCK * 150 + (size_t)chunk * 128 * 150;
  #pragma unroll
  for (int it = 0; it < 75; ++it) {               // 75*256 = 19200 = 128*150
    int f = it * 256 + tid;
    int il = f / 150, o = f - il * 150;
    tile[il * 161 + o] = f2bf(src[f]);
  }
  __syncthreads();
  size_t dstbase = (size_t)g * 160 * FCK + (size_t)chunk * 128;
  #pragma unroll
  for (int it = 0; it < 10; ++it) {               // 10*256 = 2560 = 160*16
    int wi = it * 256 + tid;
    int o = wi >> 4, il8 = (wi & 15) * 8;
    u16 vals[8];
    if (o < 150) {
      #pragma unroll
      for (int j = 0; j < 8; ++j) vals[j] = tile[(il8 + j) * 161 + o];
    } else {
      #pragma unroll
      for (int j = 0; j < 8; ++j) vals[j] = 0;
    }
    *(short8*)(wfcb + dstbase + (size_t)o * FCK + il8) = *(short8*)vals;
  }
}

// ------- crop + bilinear 2x upsample -> up3[g][b][pp(8x8 pad)][ci] bf16 -------
__global__ void __launch_bounds__(256) k_up3(const float* __restrict__ x,
                                             const int* __restrict__ cx,
                                             const int* __restrict__ cy,
                                             u16* __restrict__ up3) {
  __shared__ float crop[3][3][C_];   // [r][s][ci]
  int bg = blockIdx.x;               // b*20+g
  int b = bg / 20, g = bg % 20;
  int X = cx[bg] - 1, Y = cy[bg] - 1;
  const float* xb = x + (size_t)b * (C_*14*14);
  int t = threadIdx.x;
  for (int it = 0; it < 6; ++it) {
    int idx = it*256 + t;            // 1536 = 512*3
    int r = idx >> 9, ci = idx & 511;
    const float* srow = xb + ci*196 + (Y + r)*14 + X;
    crop[r][0][ci] = srow[0];
    crop[r][1][ci] = srow[1];
    crop[r][2][ci] = srow[2];
  }
  __syncthreads();
  const int   R0[6] = {0,0,0,1,1,1};
  const float WA[6] = {1.f, .75f, .25f, .75f, .25f, 0.f};
  u16* dstbase = up3 + ((size_t)g*B_ + b) * 64 * C_;
  for (int it = 0; it < 16; ++it) {
    int cidx = it*256 + t;           // 4096 chunks of 8 ci
    int pp = cidx >> 6;
    int c8 = (cidx & 63) * 8;
    int ph = pp >> 3, pw = pp & 7;
    u16 outv[8];
    if (ph == 0 || ph == 7 || pw == 0 || pw == 7) {
      #pragma unroll
      for (int j = 0; j < 8; ++j) outv[j] = 0;
    } else {
      int oh = ph - 1, ow = pw - 1;
      int r0 = R0[oh]; float wy0 = WA[oh], wy1 = 1.f - WA[oh];
      int s0 = R0[ow]; float wx0 = WA[ow], wx1 = 1.f - WA[ow];
      #pragma unroll
      for (int j = 0; j < 8; ++j) {
        int ci = c8 + j;
        float v = wy0*(wx0*crop[r0][s0][ci]   + wx1*crop[r0][s0+1][ci])
                + wy1*(wx0*crop[r0+1][s0][ci] + wx1*crop[r0+1][s0+1][ci]);
        outv[j] = f2bf(v);
      }
    }
    *(short8*)(dstbase + (size_t)pp*C_ + c8) = *(short8*)outv;
  }
}

// ---------------- grouped conv as implicit GEMM (bf16 MFMA) ----------------
// per group g: D[co][n] = sum_k Wb[g*512+co][k] * P[n][k],  k=t*512+ci, n=b*36+pix
// BM=256, BN=128, BK=64, 512 threads / 8 waves (4M x 2N), 64x64 out per wave.
// T3+T4+T5 counted-vmcnt pipeline: triple-buffered LDS (144 KB), stage loads
// for tile t+2 issued during step t, end-of-step wait = vmcnt(6) (waits only
// for loads issued TWO steps ago; never drains to 0 in the main loop).
// 2 phases per K-step (by kb), 16-MFMA cluster per phase under setprio(1).
__global__ void __launch_bounds__(512) k_conv(const u16* __restrict__ wb,
                                              const u16* __restrict__ up3,
                                              const float* __restrict__ conv_b,
                                              u16* __restrict__ feat) {
  __shared__ __align__(16) u16 As[3][256*64];   // 96 KB
  __shared__ __align__(16) u16 Bs[3][128*64];   // 48 KB
  int bid = blockIdx.x;
  int lid = (bid & 7) * 180 + (bid >> 3);   // bijective: 1440 = 8*180
  int mt = lid & 1;                          // innermost: A-subtile (B-reuse pair)
  int nt = (lid >> 1) % 36;                  // B-tile id
  int g  = lid / 72;                         // group
  int tid = threadIdx.x;
  int lane = tid & 63, w = tid >> 6;         // 8 waves
  int wr = w >> 1, wc = w & 1;               // wave grid 4M x 2N
  int rl = lane >> 3, s = lane & 7;
  int l15 = lane & 15, l4 = lane >> 4;

  const u16* gA[4]; int ofsA[4];
  #pragma unroll
  for (int i = 0; i < 4; ++i) {
    int rA = w*32 + i*8 + rl;                // 0..255
    int c  = s ^ (rA & 7);                   // source pre-swizzle (rule #21)
    gA[i] = wb + (size_t)(g*512 + mt*256 + rA) * K2 + c*8;
    ofsA[i] = (w*32 + i*8) * 64;
  }
  const u16* gB[2]; int ofsB[2];
  #pragma unroll
  for (int i = 0; i < 2; ++i) {
    int rB = w*16 + i*8 + rl;                // 0..127
    int n  = nt*128 + rB;
    unsigned bb = (unsigned)n / 36u;
    unsigned pix = (unsigned)n % 36u;
    int pixA = (int)(pix/6u)*8 + (int)(pix%6u);
    int c = s ^ (rB & 7);
    gB[i] = up3 + (((size_t)g*B_ + bb)*64 + pixA) * C_ + c*8;
    ofsB[i] = (w*16 + i*8) * 64;
  }

  auto kofsB_of = [&](int st) -> size_t {
    int t9 = st >> 3;
    return (size_t)((t9/3)*8 + (t9%3)) * C_ + (size_t)(st & 7) * 64;
  };
  auto stage_h1 = [&](int st) {              // A rows [0,128) + B rows [0,64)
    int b3 = st % 3;
    size_t kA = (size_t)st * 64, kB = kofsB_of(st);
    load_lds16(gA[0] + kA, &As[b3][ofsA[0]]);
    load_lds16(gA[1] + kA, &As[b3][ofsA[1]]);
    load_lds16(gB[0] + kB, &Bs[b3][ofsB[0]]);
  };
  auto stage_h2 = [&](int st) {              // A rows [128,256) + B rows [64,128)
    int b3 = st % 3;
    size_t kA = (size_t)st * 64, kB = kofsB_of(st);
    load_lds16(gA[2] + kA, &As[b3][ofsA[2]]);
    load_lds16(gA[3] + kA, &As[b3][ofsA[3]]);
    load_lds16(gB[1] + kB, &Bs[b3][ofsB[1]]);
  };

  float4v acc[4][4];
  #pragma unroll
  for (int mi = 0; mi < 4; ++mi)
    #pragma unroll
    for (int nj = 0; nj < 4; ++nj) acc[mi][nj] = (float4v){0.f,0.f,0.f,0.f};

  // prologue: tiles 0 and 1 in flight (12 loads); wait tile 0 (oldest 6)
  stage_h1(0); stage_h2(0);
  stage_h1(1); stage_h2(1);
  asm volatile("s_waitcnt vmcnt(6)" ::: "memory");
  __builtin_amdgcn_s_barrier();

  for (int t = 0; t < 72; ++t) {
    const char* curA = (const char*)As[t % 3];
    const char* curB = (const char*)Bs[t % 3];
    // ---- phase A (kb=0) ----
    {
      short8 a[4], bfr[4];
      #pragma unroll
      for (int mi = 0; mi < 4; ++mi) {
        int row = wr*64 + mi*16 + l15;
        int cb  = (l4*16) ^ ((row & 7) << 4);
        a[mi] = *(const short8*)(curA + row*128 + cb);
      }
      #pragma unroll
      for (int nj = 0; nj < 4; ++nj) {
        int row = wc*64 + nj*16 + l15;
        int cb  = (l4*16) ^ ((row & 7) << 4);
        bfr[nj] = *(const short8*)(curB + row*128 + cb);
      }
      if (t < 70) stage_h1(t + 2);
      __builtin_amdgcn_s_barrier();
      __builtin_amdgcn_s_setprio(1);
      #pragma unroll
      for (int mi = 0; mi < 4; ++mi)
        #pragma unroll
        for (int nj = 0; nj < 4; ++nj)
          acc[mi][nj] = __builtin_amdgcn_mfma_f32_16x16x32_bf16(
              a[mi], bfr[nj], acc[mi][nj], 0, 0, 0);
      __builtin_amdgcn_s_setprio(0);
      __builtin_amdgcn_s_barrier();
    }
    // ---- phase B (kb=1) ----
    {
      short8 a[4], bfr[4];
      #pragma unroll
      for (int mi = 0; mi < 4; ++mi) {
        int row = wr*64 + mi*16 + l15;
        int cb  = (64 + l4*16) ^ ((row & 7) << 4);
        a[mi] = *(const short8*)(curA + row*128 + cb);
      }
      #pragma unroll
      for (int nj = 0; nj < 4; ++nj) {
        int row = wc*64 + nj*16 + l15;
        int cb  = (64 + l4*16) ^ ((row & 7) << 4);
        bfr[nj] = *(const short8*)(curB + row*128 + cb);
      }
      if (t < 70) stage_h2(t + 2);
      __builtin_amdgcn_s_barrier();
      __builtin_amdgcn_s_setprio(1);
      #pragma unroll
      for (int mi = 0; mi < 4; ++mi)
        #pragma unroll
        for (int nj = 0; nj < 4; ++nj)
          acc[mi][nj] = __builtin_amdgcn_mfma_f32_16x16x32_bf16(
              a[mi], bfr[nj], acc[mi][nj], 0, 0, 0);
      __builtin_amdgcn_s_setprio(0);
      // end-of-step: counted wait — oldest 6 = tile t+1's loads (issued step t-1)
      if (t < 70)       { asm volatile("s_waitcnt vmcnt(6)" ::: "memory"); }
      else if (t == 70) { asm volatile("s_waitcnt vmcnt(0)" ::: "memory"); }
      __builtin_amdgcn_s_barrier();
    }
  }

  // epilogue: bias + relu -> feat[g][b][co*36+pix] (bf16)
  float bias[4][4];
  #pragma unroll
  for (int mi = 0; mi < 4; ++mi)
    #pragma unroll
    for (int r = 0; r < 4; ++r)
      bias[mi][r] = conv_b[g*512 + mt*256 + wr*64 + mi*16 + l4*4 + r];
  #pragma unroll
  for (int nj = 0; nj < 4; ++nj) {
    int n = nt*128 + wc*64 + nj*16 + l15;
    unsigned bb = (unsigned)n / 36u;
    unsigned pix = (unsigned)n % 36u;
    size_t base = ((size_t)g*B_ + bb)*FCK + pix;
    #pragma unroll
    for (int mi = 0; mi < 4; ++mi)
      #pragma unroll
      for (int r = 0; r < 4; ++r) {
        int m = mt*256 + wr*64 + mi*16 + l4*4 + r;
        float v = fmaxf(acc[mi][nj][r] + bias[mi][r], 0.f);
        feat[base + (size_t)m*36] = f2bf(v);
      }
  }
}

// ---------------- FC: per-group [128 x 18432] x [18432 x 160], split-K ----------------
__global__ void __launch_bounds__(256) k_fc(const u16* __restrict__ feat,
                                            const u16* __restrict__ wfcb,
                                            float* __restrict__ accum) {
  __shared__ __align__(16) u16 As[128*64];
  __shared__ __align__(16) u16 Bs[160*64];
  int sp = blockIdx.x;   // 0..15 k-split
  int g  = blockIdx.y;
  int tid = threadIdx.x;
  int lane = tid & 63, w = tid >> 6;
  int wr = w >> 1, wc = w & 1;
  int rl = lane >> 3, s = lane & 7;
  int l15 = lane & 15, l4 = lane >> 4;

  const u16* gA[4]; u16* lA[4];
  #pragma unroll
  for (int i = 0; i < 4; ++i) {
    int r = w*32 + i*8 + rl;
    int c = s ^ (r & 7);
    gA[i] = feat + ((size_t)g*B_ + r)*FCK + c*8;
    lA[i] = (u16*)As + (w*32 + i*8) * 64;
  }
  const u16* gB[5]; u16* lB[5];
  #pragma unroll
  for (int i = 0; i < 5; ++i) {
    int r = w*40 + i*8 + rl;
    int c = s ^ (r & 7);
    gB[i] = wfcb + ((size_t)(g*160 + r))*FCK + c*8;
    lB[i] = (u16*)Bs + (w*40 + i*8) * 64;
  }

  float4v acc[4][5];
  #pragma unroll
  for (int mi = 0; mi < 4; ++mi)
    #pragma unroll
    for (int nj = 0; nj < 5; ++nj) acc[mi][nj] = (float4v){0.f,0.f,0.f,0.f};

  size_t kbase = (size_t)sp * 1152;
  for (int stp = 0; stp < 18; ++stp) {
    size_t kofs = kbase + (size_t)stp * 64;
    __syncthreads();
    #pragma unroll
    for (int i = 0; i < 4; ++i) load_lds16(gA[i] + kofs, lA[i]);
    #pragma unroll
    for (int i = 0; i < 5; ++i) load_lds16(gB[i] + kofs, lB[i]);
    __syncthreads();

    short8 a[4][2], bf[5][2];
    #pragma unroll
    for (int kb = 0; kb < 2; ++kb) {
      #pragma unroll
      for (int mi = 0; mi < 4; ++mi) {
        int row = wr*64 + mi*16 + l15;
        int cb  = (kb*64 + l4*16) ^ ((row & 7) << 4);
        a[mi][kb] = *(const short8*)((const char*)As + row*128 + cb);
      }
      #pragma unroll
      for (int nj = 0; nj < 5; ++nj) {
        int row = wc*80 + nj*16 + l15;
        int cb  = (kb*64 + l4*16) ^ ((row & 7) << 4);
        bf[nj][kb] = *(const short8*)((const char*)Bs + row*128 + cb);
      }
    }
    #pragma unroll
    for (int kb = 0; kb < 2; ++kb)
      #pragma unroll
      for (int mi = 0; mi < 4; ++mi)
        #pragma unroll
        for (int nj = 0; nj < 5; ++nj)
          acc[mi][nj] = __builtin_amdgcn_mfma_f32_16x16x32_bf16(
              a[mi][kb], bf[nj][kb], acc[mi][nj], 0, 0, 0);
  }

  #pragma unroll
  for (int mi = 0; mi < 4; ++mi)
    #pragma unroll
    for (int r = 0; r < 4; ++r) {
      int brow = wr*64 + mi*16 + l4*4 + r;
      #pragma unroll
      for (int nj = 0; nj < 5; ++nj) {
        int o = wc*80 + nj*16 + l15;
        atomicAdd(&accum[((size_t)brow*20 + g)*160 + o], acc[mi][nj][r]);
      }
    }
}

__global__ void k_final(const float* __restrict__ accum, const float* __restrict__ fcb,
                        float* __restrict__ out) {
  int idx = blockIdx.x * 256 + threadIdx.x;     // 128*3000
  if (idx >= B_*3000) return;
  unsigned b = (unsigned)idx / 3000u;
  unsigned rem = (unsigned)idx % 3000u;
  unsigned g = rem / 150u, o = rem % 150u;
  out[idx] = fmaxf(accum[((size_t)b*20 + g)*160 + o] + fcb[g*150 + o], 0.f);
}

extern "C" void kernel_launch(void* const* d_in, const int* in_sizes, int n_in,
                              void* d_out, int out_size, void* d_ws, size_t ws_size,
                              hipStream_t stream) {
  const float* x      = (const float*)d_in[0];
  const float* y      = (const float*)d_in[1];
  const float* conv_w = (const float*)d_in[2];
  const float* conv_b = (const float*)d_in[3];
  const float* fc_w   = (const float*)d_in[4];
  const float* fc_b   = (const float*)d_in[5];
  float* out = (float*)d_out;

  char* ws = (char*)d_ws;
  size_t off = 0;
  u16* Wb   = (u16*)(ws + off); off += (size_t)10240 * K2 * 2;        // 94.4 MB
  u16* up3  = (u16*)(ws + off); off += (size_t)G_ * B_ * 64 * C_ * 2; // 167.8 MB
  u16* feat = (u16*)(ws + off); off += (size_t)G_ * B_ * FCK * 2;     // 94.4 MB
  float* accum = (float*)(ws + off); off += (size_t)B_ * G_ * 160 * 4;// 1.6 MB
  int* cx = (int*)(ws + off); off += B_ * G_ * 4;
  int* cy = (int*)(ws + off); off += B_ * G_ * 4;
  u16* Wfcb = up3;   // alias: fc weights built AFTER conv consumed up3 (peak ws 358 MB)

  k_pos<<<1, 128, 0, stream>>>(y, cx, cy);
  k_convw<<<(10240*512)/256, 256, 0, stream>>>(conv_w, Wb);
  k_up3<<<B_*G_, 256, 0, stream>>>(x, cx, cy, up3);
  hipMemsetAsync(accum, 0, (size_t)B_ * G_ * 160 * 4, stream);
  k_conv<<<1440, 512, 0, stream>>>(Wb, up3, conv_b, feat);
  k_fcw<<<dim3(144, 20), 256, 0, stream>>>(fc_w, Wfcb);
  k_fc<<<dim3(16, 20), 256, 0, stream>>>(feat, Wfcb, accum);
  k_final<<<(B_*3000 + 255)/256, 256, 0, stream>>>(accum, fc_b, out);
}

// Round 5
// 630.318 us; speedup vs baseline: 1.1359x; 1.1359x over previous
//
#include <hip/hip_runtime.h>
#include <stdint.h>

#define B_  128
#define C_  512
#define G_  20
#define K2  4608      // C_*9, conv GEMM K
#define FCK 18432     // C_*36, fc GEMM K

typedef unsigned short u16;
typedef unsigned int   u32;
typedef __attribute__((ext_vector_type(8))) short  short8;
typedef __attribute__((ext_vector_type(4))) float  float4v;

__device__ __forceinline__ u16 f2bf(float f) {
  u32 u = __builtin_bit_cast(u32, f);
  u = (u + 0x7fffu + ((u >> 16) & 1u)) >> 16;   // RNE
  return (u16)u;
}

__device__ __forceinline__ void load_lds16(const void* g, void* l) {
  __builtin_amdgcn_global_load_lds(
      (const __attribute__((address_space(1))) void*)(uintptr_t)g,
      (__attribute__((address_space(3))) void*)(uint32_t)(uintptr_t)l,
      16, 0, 0);
}

#define BAR() __builtin_amdgcn_s_barrier()
#define LGKM0() do { asm volatile("s_waitcnt lgkmcnt(0)" ::: "memory"); \
                     __builtin_amdgcn_sched_barrier(0); } while (0)

// ---------------- landmarks -> integer crop positions ----------------
__global__ void k_pos(const float* __restrict__ y, int* __restrict__ cx, int* __restrict__ cy) {
  int b = blockIdx.x * blockDim.x + threadIdx.x;
  if (b >= B_) return;
  const int   I1[10] = {21,18,19,41,38,49,48,51,61,56};
  const int   I2[10] = {22,25,24,46,43,53,54,57,63,58};
  const float CF[10] = {-0.5f, -1.0f/3.0f, 1.0f/3.0f, 1.0f, 0.f,0.f,0.f,0.f,0.f, 0.5f};
  const float* yb = y + b * 136;
  float ruler = fabsf(yb[2*39] - yb[2*42]);
  for (int j = 0; j < 10; ++j) {
    float off = ruler * CF[j];
    float vx1 = yb[2*I1[j]];
    float vy1 = yb[2*I1[j]+1] + off;
    float vx2 = yb[2*I2[j]];
    float vy2 = yb[2*I2[j]+1] + off;
    int px1 = (int)(vx1 * 0.0625f); px1 = min(max(px1,1),12);
    int py1 = (int)(vy1 * 0.0625f); py1 = min(max(py1,1),12);
    int px2 = (int)(vx2 * 0.0625f); px2 = min(max(px2,1),12);
    int py2 = (int)(vy2 * 0.0625f); py2 = min(max(py2,1),12);
    cx[b*20 + 2*j]   = px1;  cx[b*20 + 2*j+1] = px2;
    cy[b*20 + 2*j]   = py1;  cy[b*20 + 2*j+1] = py2;
  }
}

// ------------- conv_w f32 [o][ci][t] -> bf16 Wb[o][t*512+ci] -------------
__global__ void k_convw(const float* __restrict__ w, u16* __restrict__ wb) {
  int tid = blockIdx.x * 256 + threadIdx.x;       // 10240*512 threads
  int o = tid >> 9, ci = tid & 511;
  const float* src = w + (size_t)tid * 9;         // (o*512+ci)*9
  u16* dst = wb + (size_t)o * K2 + ci;
  #pragma unroll
  for (int t = 0; t < 9; ++t) dst[t*512] = f2bf(src[t]);
}

// ------- fc_w f32 [g][i][o:150] -> bf16 Wfcb[g][o:160(pad0)][i] -------
__global__ void __launch_bounds__(256) k_fcw(const float* __restrict__ fw, u16* __restrict__ wfcb) {
  __shared__ u16 tile[128 * 161];                 // [il][o], stride 161 (conflict pad)
  int chunk = blockIdx.x;                         // 0..143 (FCK/128)
  int g     = blockIdx.y;
  int tid   = threadIdx.x;
  const float* src = fw + (size_t)g * FCK * 150 + (size_t)chunk * 128 * 150;
  #pragma unroll
  for (int it = 0; it < 75; ++it) {               // 75*256 = 19200 = 128*150
    int f = it * 256 + tid;
    int il = f / 150, o = f - il * 150;
    tile[il * 161 + o] = f2bf(src[f]);
  }
  __syncthreads();
  size_t dstbase = (size_t)g * 160 * FCK + (size_t)chunk * 128;
  #pragma unroll
  for (int it = 0; it < 10; ++it) {               // 10*256 = 2560 = 160*16
    int wi = it * 256 + tid;
    int o = wi >> 4, il8 = (wi & 15) * 8;
    u16 vals[8];
    if (o < 150) {
      #pragma unroll
      for (int j = 0; j < 8; ++j) vals[j] = tile[(il8 + j) * 161 + o];
    } else {
      #pragma unroll
      for (int j = 0; j < 8; ++j) vals[j] = 0;
    }
    *(short8*)(wfcb + dstbase + (size_t)o * FCK + il8) = *(short8*)vals;
  }
}

// ------- crop + bilinear 2x upsample -> up3[g][b][pp(8x8 pad)][ci] bf16 -------
__global__ void __launch_bounds__(256) k_up3(const float* __restrict__ x,
                                             const int* __restrict__ cx,
                                             const int* __restrict__ cy,
                                             u16* __restrict__ up3) {
  __shared__ float crop[3][3][C_];   // [r][s][ci]
  int bg = blockIdx.x;               // b*20+g
  int b = bg / 20, g = bg % 20;
  int X = cx[bg] - 1, Y = cy[bg] - 1;
  const float* xb = x + (size_t)b * (C_*14*14);
  int t = threadIdx.x;
  for (int it = 0; it < 6; ++it) {
    int idx = it*256 + t;            // 1536 = 512*3
    int r = idx >> 9, ci = idx & 511;
    const float* srow = xb + ci*196 + (Y + r)*14 + X;
    crop[r][0][ci] = srow[0];
    crop[r][1][ci] = srow[1];
    crop[r][2][ci] = srow[2];
  }
  __syncthreads();
  const int   R0[6] = {0,0,0,1,1,1};
  const float WA[6] = {1.f, .75f, .25f, .75f, .25f, 0.f};
  u16* dstbase = up3 + ((size_t)g*B_ + b) * 64 * C_;
  for (int it = 0; it < 16; ++it) {
    int cidx = it*256 + t;           // 4096 chunks of 8 ci
    int pp = cidx >> 6;
    int c8 = (cidx & 63) * 8;
    int ph = pp >> 3, pw = pp & 7;
    u16 outv[8];
    if (ph == 0 || ph == 7 || pw == 0 || pw == 7) {
      #pragma unroll
      for (int j = 0; j < 8; ++j) outv[j] = 0;
    } else {
      int oh = ph - 1, ow = pw - 1;
      int r0 = R0[oh]; float wy0 = WA[oh], wy1 = 1.f - WA[oh];
      int s0 = R0[ow]; float wx0 = WA[ow], wx1 = 1.f - WA[ow];
      #pragma unroll
      for (int j = 0; j < 8; ++j) {
        int ci = c8 + j;
        float v = wy0*(wx0*crop[r0][s0][ci]   + wx1*crop[r0][s0+1][ci])
                + wy1*(wx0*crop[r0+1][s0][ci] + wx1*crop[r0+1][s0+1][ci]);
        outv[j] = f2bf(v);
      }
    }
    *(short8*)(dstbase + (size_t)pp*C_ + c8) = *(short8*)outv;
  }
}

// ---------------- grouped conv as implicit GEMM, 8-phase template ----------------
// per group g: D[co][n] = sum_k Wb[g*512+co][k] * P[n][k],  k=t*512+ci, n=b*36+pix
// BM=256, BN=256, BK=64. 512 thr / 8 waves (2M x 4N), per-wave 128x64 (acc 8x4).
// dbuf-2 LDS 128 KB; even K-tile in buf0, odd in buf1. 36 iters x 8 phases;
// phase = {ds_reads | stage half-tile -> bar -> lgkm0 -> 16 MFMA (setprio) -> bar}.
// Region reads: A halves at ph1&ph3 (ph5&ph7), B halves at ph1&ph2 (ph5&ph6).
// Stage slots (iter i, tiles t=2i,t+1): ph3 B0(t+2), ph4 B1+A0(t+2), ph5 A1(t+2),
// ph7 B0(t+3), ph8 B1+A0+A1(t+3). Waits: ph4-end vmcnt(6) [newest 6 = own ph3+ph4
// stages; everything older (tile t+1, staged prev iter ph7/ph8) landed]; ph8-end
// vmcnt(8) [newest 8 = tile t+3; tile t+2 (ph3/4/5) landed]. Last iter drains.
__global__ void __launch_bounds__(512, 2) k_conv(const u16* __restrict__ wb,
                                                 const u16* __restrict__ up3,
                                                 const float* __restrict__ conv_b,
                                                 u16* __restrict__ feat) {
  __shared__ __align__(16) u16 As[2 * 256 * 64];   // 64 KB (2 dbuf)
  __shared__ __align__(16) u16 Bs[2 * 256 * 64];   // 64 KB
  int bid = blockIdx.x;
  int lid = (bid & 7) * 90 + (bid >> 3);    // bijective: 720 = 8*90
  int mt = lid & 1;                          // innermost: B-tile reuse pair
  int nt = (lid >> 1) % 18;
  int g  = lid / 36;
  int tid = threadIdx.x;
  int lane = tid & 63;
  int w = tid >> 6;                          // 8 waves
  int wr = w >> 2, wc = w & 3;               // 2M x 4N
  int l15 = lane & 15, l4 = lane >> 4;

  // ---- staging addresses (pre-swizzled source, linear LDS dest; rule #21) ----
  // thread covers (row_local, slot): idx = j*512+tid; rl = idx>>3, sl = idx&7.
  int rl0 = tid >> 3, sl0 = tid & 7;
  // A: one base pointer; rows contiguous (j adds 64 rows, h adds 128 rows).
  const u16* srcA0 = wb + (size_t)(g*512 + mt*256 + rl0) * K2 + (sl0 ^ (rl0 & 7)) * 8;
  // B: 4 base pointers (row -> (b,pix) is non-affine).
  const u16* srcB[2][2];
  #pragma unroll
  for (int h = 0; h < 2; ++h)
    #pragma unroll
    for (int j = 0; j < 2; ++j) {
      int rl = j * 64 + rl0;                 // within half: 0..127
      int n  = nt * 256 + h * 128 + rl;
      unsigned bb = (unsigned)n / 36u;
      unsigned pix = (unsigned)n % 36u;
      int pixA = (int)(pix / 6u) * 8 + (int)(pix % 6u);
      srcB[h][j] = up3 + (((size_t)g*B_ + bb)*64 + pixA) * C_ + (sl0 ^ (rl0 & 7)) * 8;
    }

  auto stageA = [&](int st, int h) {         // half-tile: 2 loads/wave
    if (st >= 72) return;
    int db = st & 1;
    size_t ko = (size_t)st * 64;
    #pragma unroll
    for (int j = 0; j < 2; ++j)
      load_lds16(srcA0 + (size_t)(h*128 + j*64) * K2 + ko,
                 (char*)As + db*32768 + h*16384 + (j*512 + tid)*16);
  };
  auto stageB = [&](int st, int h) {
    if (st >= 72) return;
    int db = st & 1;
    int t9 = st >> 3;
    size_t ko = (size_t)((t9/3)*8 + (t9%3)) * C_ + (size_t)(st & 7) * 64;
    #pragma unroll
    for (int j = 0; j < 2; ++j)
      load_lds16(srcB[h][j] + ko,
                 (char*)Bs + db*32768 + h*16384 + (j*512 + tid)*16);
  };

  auto ldfrag = [&](const char* base, int row, int kb) -> short8 {
    int cb = (kb*64 + l4*16) ^ ((row & 7) << 4);
    return *(const short8*)(base + row*128 + cb);
  };

  float4v acc[8][4];
  #pragma unroll
  for (int mi = 0; mi < 8; ++mi)
    #pragma unroll
    for (int nj = 0; nj < 4; ++nj) acc[mi][nj] = (float4v){0.f,0.f,0.f,0.f};

  // ---- prologue: tiles 0 (buf0) and 1 (buf1); wait tile 0 (newest 8 = tile 1) ----
  stageB(0,0); stageB(0,1); stageA(0,0); stageA(0,1);
  stageB(1,0); stageB(1,1); stageA(1,0); stageA(1,1);
  asm volatile("s_waitcnt vmcnt(8)" ::: "memory");
  BAR();

  short8 aF[4][2], b01[2][2], b23[2][2];

#define LDA_HALF(BASE, MH)                                        \
  _Pragma("unroll") for (int mi = 0; mi < 4; ++mi)                \
    _Pragma("unroll") for (int kb = 0; kb < 2; ++kb)              \
      aF[mi][kb] = ldfrag(BASE, wr*128 + ((MH)*4 + mi)*16 + l15, kb);
#define LDB_HALF(BASE, NH, DST)                                   \
  _Pragma("unroll") for (int nj = 0; nj < 2; ++nj)                \
    _Pragma("unroll") for (int kb = 0; kb < 2; ++kb)              \
      DST[nj][kb] = ldfrag(BASE, wc*64 + ((NH)*2 + nj)*16 + l15, kb);
#define MFMA_QUAD(BF, QM, QN)                                     \
  __builtin_amdgcn_s_setprio(1);                                  \
  _Pragma("unroll") for (int kb = 0; kb < 2; ++kb)                \
    _Pragma("unroll") for (int mi = 0; mi < 4; ++mi)              \
      _Pragma("unroll") for (int nj = 0; nj < 2; ++nj)            \
        acc[(QM)*4+mi][(QN)*2+nj] = __builtin_amdgcn_mfma_f32_16x16x32_bf16( \
            aF[mi][kb], BF[nj][kb], acc[(QM)*4+mi][(QN)*2+nj], 0, 0, 0);     \
  __builtin_amdgcn_s_setprio(0);

  for (int it = 0; it < 36; ++it) {
    int t0 = 2 * it;
    const char* A0 = (const char*)As;
    const char* B0 = (const char*)Bs;
    const char* A1 = (const char*)As + 32768;
    const char* B1 = (const char*)Bs + 32768;
    // ---- ph1: Q00 of tile t0 ----
    LDA_HALF(A0, 0); LDB_HALF(B0, 0, b01);
    BAR(); LGKM0(); MFMA_QUAD(b01, 0, 0); BAR();
    // ---- ph2: Q01 ----
    LDB_HALF(B0, 1, b23);
    BAR(); LGKM0(); MFMA_QUAD(b23, 0, 1); BAR();
    // ---- ph3: Q10 ----
    LDA_HALF(A0, 1);
    stageB(t0 + 2, 0);
    BAR(); LGKM0(); MFMA_QUAD(b01, 1, 0); BAR();
    // ---- ph4: Q11 ----
    stageB(t0 + 2, 1); stageA(t0 + 2, 0);
    BAR(); LGKM0(); MFMA_QUAD(b23, 1, 1);
    if (it < 35) { asm volatile("s_waitcnt vmcnt(6)" ::: "memory"); }
    else         { asm volatile("s_waitcnt vmcnt(0)" ::: "memory"); }
    BAR();
    // ---- ph5: Q00 of tile t0+1 ----
    LDA_HALF(A1, 0); LDB_HALF(B1, 0, b01);
    stageA(t0 + 2, 1);
    BAR(); LGKM0(); MFMA_QUAD(b01, 0, 0); BAR();
    // ---- ph6: Q01 ----
    LDB_HALF(B1, 1, b23);
    BAR(); LGKM0(); MFMA_QUAD(b23, 0, 1); BAR();
    // ---- ph7: Q10 ----
    LDA_HALF(A1, 1);
    stageB(t0 + 3, 0);
    BAR(); LGKM0(); MFMA_QUAD(b01, 1, 0); BAR();
    // ---- ph8: Q11 ----
    stageB(t0 + 3, 1); stageA(t0 + 3, 0); stageA(t0 + 3, 1);
    BAR(); LGKM0(); MFMA_QUAD(b23, 1, 1);
    asm volatile("s_waitcnt vmcnt(8)" ::: "memory");
    BAR();
  }
#undef LDA_HALF
#undef LDB_HALF
#undef MFMA_QUAD

  // ---- epilogue: bias + relu -> feat[g][b][co*36+pix] (bf16) ----
  float bias[8][4];
  #pragma unroll
  for (int mi = 0; mi < 8; ++mi)
    #pragma unroll
    for (int r = 0; r < 4; ++r)
      bias[mi][r] = conv_b[g*512 + mt*256 + wr*128 + mi*16 + l4*4 + r];
  #pragma unroll
  for (int nj = 0; nj < 4; ++nj) {
    int n = nt*256 + wc*64 + nj*16 + l15;
    unsigned bb = (unsigned)n / 36u;
    unsigned pix = (unsigned)n % 36u;
    size_t base = ((size_t)g*B_ + bb)*FCK + pix;
    #pragma unroll
    for (int mi = 0; mi < 8; ++mi)
      #pragma unroll
      for (int r = 0; r < 4; ++r) {
        int m = mt*256 + wr*128 + mi*16 + l4*4 + r;
        float v = fmaxf(acc[mi][nj][r] + bias[mi][r], 0.f);
        feat[base + (size_t)m*36] = f2bf(v);
      }
  }
}

// ---------------- FC: per-group [128 x 18432] x [18432 x 160], split-K ----------------
__global__ void __launch_bounds__(256) k_fc(const u16* __restrict__ feat,
                                            const u16* __restrict__ wfcb,
                                            float* __restrict__ accum) {
  __shared__ __align__(16) u16 As[128*64];
  __shared__ __align__(16) u16 Bs[160*64];
  int sp = blockIdx.x;   // 0..15 k-split
  int g  = blockIdx.y;
  int tid = threadIdx.x;
  int lane = tid & 63, w = tid >> 6;
  int wr = w >> 1, wc = w & 1;
  int rl = lane >> 3, s = lane & 7;
  int l15 = lane & 15, l4 = lane >> 4;

  const u16* gA[4]; u16* lA[4];
  #pragma unroll
  for (int i = 0; i < 4; ++i) {
    int r = w*32 + i*8 + rl;
    int c = s ^ (r & 7);
    gA[i] = feat + ((size_t)g*B_ + r)*FCK + c*8;
    lA[i] = (u16*)As + (w*32 + i*8) * 64;
  }
  const u16* gB[5]; u16* lB[5];
  #pragma unroll
  for (int i = 0; i < 5; ++i) {
    int r = w*40 + i*8 + rl;
    int c = s ^ (r & 7);
    gB[i] = wfcb + ((size_t)(g*160 + r))*FCK + c*8;
    lB[i] = (u16*)Bs + (w*40 + i*8) * 64;
  }

  float4v acc[4][5];
  #pragma unroll
  for (int mi = 0; mi < 4; ++mi)
    #pragma unroll
    for (int nj = 0; nj < 5; ++nj) acc[mi][nj] = (float4v){0.f,0.f,0.f,0.f};

  size_t kbase = (size_t)sp * 1152;
  for (int stp = 0; stp < 18; ++stp) {
    size_t kofs = kbase + (size_t)stp * 64;
    __syncthreads();
    #pragma unroll
    for (int i = 0; i < 4; ++i) load_lds16(gA[i] + kofs, lA[i]);
    #pragma unroll
    for (int i = 0; i < 5; ++i) load_lds16(gB[i] + kofs, lB[i]);
    __syncthreads();

    short8 a[4][2], bf[5][2];
    #pragma unroll
    for (int kb = 0; kb < 2; ++kb) {
      #pragma unroll
      for (int mi = 0; mi < 4; ++mi) {
        int row = wr*64 + mi*16 + l15;
        int cb  = (kb*64 + l4*16) ^ ((row & 7) << 4);
        a[mi][kb] = *(const short8*)((const char*)As + row*128 + cb);
      }
      #pragma unroll
      for (int nj = 0; nj < 5; ++nj) {
        int row = wc*80 + nj*16 + l15;
        int cb  = (kb*64 + l4*16) ^ ((row & 7) << 4);
        bf[nj][kb] = *(const short8*)((const char*)Bs + row*128 + cb);
      }
    }
    #pragma unroll
    for (int kb = 0; kb < 2; ++kb)
      #pragma unroll
      for (int mi = 0; mi < 4; ++mi)
        #pragma unroll
        for (int nj = 0; nj < 5; ++nj)
          acc[mi][nj] = __builtin_amdgcn_mfma_f32_16x16x32_bf16(
              a[mi][kb], bf[nj][kb], acc[mi][nj], 0, 0, 0);
  }

  #pragma unroll
  for (int mi = 0; mi < 4; ++mi)
    #pragma unroll
    for (int r = 0; r < 4; ++r) {
      int brow = wr*64 + mi*16 + l4*4 + r;
      #pragma unroll
      for (int nj = 0; nj < 5; ++nj) {
        int o = wc*80 + nj*16 + l15;
        atomicAdd(&accum[((size_t)brow*20 + g)*160 + o], acc[mi][nj][r]);
      }
    }
}

__global__ void k_final(const float* __restrict__ accum, const float* __restrict__ fcb,
                        float* __restrict__ out) {
  int idx = blockIdx.x * 256 + threadIdx.x;     // 128*3000
  if (idx >= B_*3000) return;
  unsigned b = (unsigned)idx / 3000u;
  unsigned rem = (unsigned)idx % 3000u;
  unsigned g = rem / 150u, o = rem % 150u;
  out[idx] = fmaxf(accum[((size_t)b*20 + g)*160 + o] + fcb[g*150 + o], 0.f);
}

extern "C" void kernel_launch(void* const* d_in, const int* in_sizes, int n_in,
                              void* d_out, int out_size, void* d_ws, size_t ws_size,
                              hipStream_t stream) {
  const float* x      = (const float*)d_in[0];
  const float* y      = (const float*)d_in[1];
  const float* conv_w = (const float*)d_in[2];
  const float* conv_b = (const float*)d_in[3];
  const float* fc_w   = (const float*)d_in[4];
  const float* fc_b   = (const float*)d_in[5];
  float* out = (float*)d_out;

  char* ws = (char*)d_ws;
  size_t off = 0;
  u16* Wb   = (u16*)(ws + off); off += (size_t)10240 * K2 * 2;        // 94.4 MB
  u16* up3  = (u16*)(ws + off); off += (size_t)G_ * B_ * 64 * C_ * 2; // 167.8 MB
  u16* feat = (u16*)(ws + off); off += (size_t)G_ * B_ * FCK * 2;     // 94.4 MB
  float* accum = (float*)(ws + off); off += (size_t)B_ * G_ * 160 * 4;// 1.6 MB
  int* cx = (int*)(ws + off); off += B_ * G_ * 4;
  int* cy = (int*)(ws + off); off += B_ * G_ * 4;
  u16* Wfcb = up3;   // alias: fc weights built AFTER conv consumed up3 (peak ws 358 MB)

  k_pos<<<1, 128, 0, stream>>>(y, cx, cy);
  k_convw<<<(10240*512)/256, 256, 0, stream>>>(conv_w, Wb);
  k_up3<<<B_*G_, 256, 0, stream>>>(x, cx, cy, up3);
  hipMemsetAsync(accum, 0, (size_t)B_ * G_ * 160 * 4, stream);
  k_conv<<<720, 512, 0, stream>>>(Wb, up3, conv_b, feat);
  k_fcw<<<dim3(144, 20), 256, 0, stream>>>(fc_w, Wfcb);
  k_fc<<<dim3(16, 20), 256, 0, stream>>>(feat, Wfcb, accum);
  k_final<<<(B_*3000 + 255)/256, 256, 0, stream>>>(accum, fc_b, out);
}

// Round 6
// 629.075 us; speedup vs baseline: 1.1382x; 1.0020x over previous
//
#include <hip/hip_runtime.h>
#include <stdint.h>

#define B_  128
#define C_  512
#define G_  20
#define K2  4608      // C_*9, conv GEMM K
#define FCK 18432     // C_*36, fc GEMM K

typedef unsigned short u16;
typedef unsigned int   u32;
typedef __attribute__((ext_vector_type(8))) short  short8;
typedef __attribute__((ext_vector_type(4))) float  float4v;

__device__ __forceinline__ u16 f2bf(float f) {
  u32 u = __builtin_bit_cast(u32, f);
  u = (u + 0x7fffu + ((u >> 16) & 1u)) >> 16;   // RNE
  return (u16)u;
}

__device__ __forceinline__ void load_lds16(const void* g, void* l) {
  __builtin_amdgcn_global_load_lds(
      (const __attribute__((address_space(1))) void*)(uintptr_t)g,
      (__attribute__((address_space(3))) void*)(uint32_t)(uintptr_t)l,
      16, 0, 0);
}

#define BAR() __builtin_amdgcn_s_barrier()

// ---------------- landmarks -> integer crop positions ----------------
__global__ void k_pos(const float* __restrict__ y, int* __restrict__ cx, int* __restrict__ cy) {
  int b = blockIdx.x * blockDim.x + threadIdx.x;
  if (b >= B_) return;
  const int   I1[10] = {21,18,19,41,38,49,48,51,61,56};
  const int   I2[10] = {22,25,24,46,43,53,54,57,63,58};
  const float CF[10] = {-0.5f, -1.0f/3.0f, 1.0f/3.0f, 1.0f, 0.f,0.f,0.f,0.f,0.f, 0.5f};
  const float* yb = y + b * 136;
  float ruler = fabsf(yb[2*39] - yb[2*42]);
  for (int j = 0; j < 10; ++j) {
    float off = ruler * CF[j];
    float vx1 = yb[2*I1[j]];
    float vy1 = yb[2*I1[j]+1] + off;
    float vx2 = yb[2*I2[j]];
    float vy2 = yb[2*I2[j]+1] + off;
    int px1 = (int)(vx1 * 0.0625f); px1 = min(max(px1,1),12);
    int py1 = (int)(vy1 * 0.0625f); py1 = min(max(py1,1),12);
    int px2 = (int)(vx2 * 0.0625f); px2 = min(max(px2,1),12);
    int py2 = (int)(vy2 * 0.0625f); py2 = min(max(py2,1),12);
    cx[b*20 + 2*j]   = px1;  cx[b*20 + 2*j+1] = px2;
    cy[b*20 + 2*j]   = py1;  cy[b*20 + 2*j+1] = py2;
  }
}

// ------------- conv_w f32 [o][ci][t] -> bf16 Wb[o][t*512+ci] -------------
__global__ void k_convw(const float* __restrict__ w, u16* __restrict__ wb) {
  int tid = blockIdx.x * 256 + threadIdx.x;       // 10240*512 threads
  int o = tid >> 9, ci = tid & 511;
  const float* src = w + (size_t)tid * 9;         // (o*512+ci)*9
  u16* dst = wb + (size_t)o * K2 + ci;
  #pragma unroll
  for (int t = 0; t < 9; ++t) dst[t*512] = f2bf(src[t]);
}

// ------- fc_w f32 [g][i][o:150] -> bf16 Wfcb[g][o:160(pad0)][i] -------
__global__ void __launch_bounds__(256) k_fcw(const float* __restrict__ fw, u16* __restrict__ wfcb) {
  __shared__ u16 tile[128 * 161];                 // [il][o], stride 161 (conflict pad)
  int chunk = blockIdx.x;                         // 0..143 (FCK/128)
  int g     = blockIdx.y;
  int tid   = threadIdx.x;
  const float* src = fw + (size_t)g * FCK * 150 + (size_t)chunk * 128 * 150;
  #pragma unroll
  for (int it = 0; it < 75; ++it) {               // 75*256 = 19200 = 128*150
    int f = it * 256 + tid;
    int il = f / 150, o = f - il * 150;
    tile[il * 161 + o] = f2bf(src[f]);
  }
  __syncthreads();
  size_t dstbase = (size_t)g * 160 * FCK + (size_t)chunk * 128;
  #pragma unroll
  for (int it = 0; it < 10; ++it) {               // 10*256 = 2560 = 160*16
    int wi = it * 256 + tid;
    int o = wi >> 4, il8 = (wi & 15) * 8;
    u16 vals[8];
    if (o < 150) {
      #pragma unroll
      for (int j = 0; j < 8; ++j) vals[j] = tile[(il8 + j) * 161 + o];
    } else {
      #pragma unroll
      for (int j = 0; j < 8; ++j) vals[j] = 0;
    }
    *(short8*)(wfcb + dstbase + (size_t)o * FCK + il8) = *(short8*)vals;
  }
}

// ------- crop + bilinear 2x upsample -> up3[g][b][pp(8x8 pad)][ci] bf16 -------
__global__ void __launch_bounds__(256) k_up3(const float* __restrict__ x,
                                             const int* __restrict__ cx,
                                             const int* __restrict__ cy,
                                             u16* __restrict__ up3) {
  __shared__ float crop[3][3][C_];   // [r][s][ci]
  int bg = blockIdx.x;               // b*20+g
  int b = bg / 20, g = bg % 20;
  int X = cx[bg] - 1, Y = cy[bg] - 1;
  const float* xb = x + (size_t)b * (C_*14*14);
  int t = threadIdx.x;
  for (int it = 0; it < 6; ++it) {
    int idx = it*256 + t;            // 1536 = 512*3
    int r = idx >> 9, ci = idx & 511;
    const float* srow = xb + ci*196 + (Y + r)*14 + X;
    crop[r][0][ci] = srow[0];
    crop[r][1][ci] = srow[1];
    crop[r][2][ci] = srow[2];
  }
  __syncthreads();
  const int   R0[6] = {0,0,0,1,1,1};
  const float WA[6] = {1.f, .75f, .25f, .75f, .25f, 0.f};
  u16* dstbase = up3 + ((size_t)g*B_ + b) * 64 * C_;
  for (int it = 0; it < 16; ++it) {
    int cidx = it*256 + t;           // 4096 chunks of 8 ci
    int pp = cidx >> 6;
    int c8 = (cidx & 63) * 8;
    int ph = pp >> 3, pw = pp & 7;
    u16 outv[8];
    if (ph == 0 || ph == 7 || pw == 0 || pw == 7) {
      #pragma unroll
      for (int j = 0; j < 8; ++j) outv[j] = 0;
    } else {
      int oh = ph - 1, ow = pw - 1;
      int r0 = R0[oh]; float wy0 = WA[oh], wy1 = 1.f - WA[oh];
      int s0 = R0[ow]; float wx0 = WA[ow], wx1 = 1.f - WA[ow];
      #pragma unroll
      for (int j = 0; j < 8; ++j) {
        int ci = c8 + j;
        float v = wy0*(wx0*crop[r0][s0][ci]   + wx1*crop[r0][s0+1][ci])
                + wy1*(wx0*crop[r0+1][s0][ci] + wx1*crop[r0+1][s0+1][ci]);
        outv[j] = f2bf(v);
      }
    }
    *(short8*)(dstbase + (size_t)pp*C_ + c8) = *(short8*)outv;
  }
}

// ---------------- grouped conv as implicit GEMM, 8-phase template ----------------
// per group g: D[co][n] = sum_k Wb[g*512+co][k] * P[n][k],  k=t*512+ci, n=b*36+pix
// BM=256, BN=256, BK=64. 512 thr / 8 waves (2M x 4N), per-wave 128x64 (acc 8x4).
// dbuf-2 LDS 128 KB. 36 iters x 8 phases. NO explicit lgkmcnt drain: ds_reads
// are compiler-visible loads, so hipcc emits fine-grained lgkmcnt(N) per
// operand (guide: near-optimal); forcing lgkmcnt(0)+sched_barrier cost ~440
// cyc/phase in round 5. Counted vmcnt only at ph4/ph8 (per derivation below).
// Stage slots (iter i, tiles t=2i,t+1): ph3 B0(t+2), ph4 B1+A0(t+2), ph5 A1(t+2),
// ph7 B0(t+3), ph8 B1+A0+A1(t+3). Waits: ph4-end vmcnt(6), ph8-end vmcnt(8).
__global__ void __launch_bounds__(512, 2) k_conv(const u16* __restrict__ wb,
                                                 const u16* __restrict__ up3,
                                                 const float* __restrict__ conv_b,
                                                 u16* __restrict__ feat) {
  __shared__ __align__(16) u16 As[2 * 256 * 64];   // 64 KB (2 dbuf)
  __shared__ __align__(16) u16 Bs[2 * 256 * 64];   // 64 KB
  int bid = blockIdx.x;
  int lid = (bid & 7) * 90 + (bid >> 3);    // bijective: 720 = 8*90
  int mt = lid & 1;                          // innermost: B-tile reuse pair
  int nt = (lid >> 1) % 18;
  int g  = lid / 36;
  int tid = threadIdx.x;
  int lane = tid & 63;
  int w = tid >> 6;                          // 8 waves
  int wr = w >> 2, wc = w & 3;               // 2M x 4N
  int l15 = lane & 15, l4 = lane >> 4;

  // ---- staging addresses (pre-swizzled source, linear LDS dest; rule #21) ----
  int rl0 = tid >> 3, sl0 = tid & 7;
  const u16* srcA0 = wb + (size_t)(g*512 + mt*256 + rl0) * K2 + (sl0 ^ (rl0 & 7)) * 8;
  const u16* srcB[2][2];
  #pragma unroll
  for (int h = 0; h < 2; ++h)
    #pragma unroll
    for (int j = 0; j < 2; ++j) {
      int rl = j * 64 + rl0;                 // within half: 0..127
      int n  = nt * 256 + h * 128 + rl;
      unsigned bb = (unsigned)n / 36u;
      unsigned pix = (unsigned)n % 36u;
      int pixA = (int)(pix / 6u) * 8 + (int)(pix % 6u);
      srcB[h][j] = up3 + (((size_t)g*B_ + bb)*64 + pixA) * C_ + (sl0 ^ (rl0 & 7)) * 8;
    }

  auto stageA = [&](int st, int h) {         // half-tile: 2 loads/thread-slot
    if (st >= 72) return;
    int db = st & 1;
    size_t ko = (size_t)st * 64;
    #pragma unroll
    for (int j = 0; j < 2; ++j)
      load_lds16(srcA0 + (size_t)(h*128 + j*64) * K2 + ko,
                 (char*)As + db*32768 + h*16384 + (j*512 + tid)*16);
  };
  auto stageB = [&](int st, int h) {
    if (st >= 72) return;
    int db = st & 1;
    int t9 = st >> 3;
    size_t ko = (size_t)((t9/3)*8 + (t9%3)) * C_ + (size_t)(st & 7) * 64;
    #pragma unroll
    for (int j = 0; j < 2; ++j)
      load_lds16(srcB[h][j] + ko,
                 (char*)Bs + db*32768 + h*16384 + (j*512 + tid)*16);
  };

  auto ldfrag = [&](const char* base, int row, int kb) -> short8 {
    int cb = (kb*64 + l4*16) ^ ((row & 7) << 4);
    return *(const short8*)(base + row*128 + cb);
  };

  float4v acc[8][4];
  #pragma unroll
  for (int mi = 0; mi < 8; ++mi)
    #pragma unroll
    for (int nj = 0; nj < 4; ++nj) acc[mi][nj] = (float4v){0.f,0.f,0.f,0.f};

  // ---- prologue: tiles 0 (buf0) and 1 (buf1); wait tile 0 (newest 8 = tile 1) ----
  stageB(0,0); stageB(0,1); stageA(0,0); stageA(0,1);
  stageB(1,0); stageB(1,1); stageA(1,0); stageA(1,1);
  asm volatile("s_waitcnt vmcnt(8)" ::: "memory");
  BAR();

  short8 aF[4][2], b01[2][2], b23[2][2];

#define LDA_HALF(BASE, MH)                                        \
  _Pragma("unroll") for (int mi = 0; mi < 4; ++mi)                \
    _Pragma("unroll") for (int kb = 0; kb < 2; ++kb)              \
      aF[mi][kb] = ldfrag(BASE, wr*128 + ((MH)*4 + mi)*16 + l15, kb);
#define LDB_HALF(BASE, NH, DST)                                   \
  _Pragma("unroll") for (int nj = 0; nj < 2; ++nj)                \
    _Pragma("unroll") for (int kb = 0; kb < 2; ++kb)              \
      DST[nj][kb] = ldfrag(BASE, wc*64 + ((NH)*2 + nj)*16 + l15, kb);
#define MFMA_QUAD(BF, QM, QN)                                     \
  __builtin_amdgcn_s_setprio(1);                                  \
  _Pragma("unroll") for (int kb = 0; kb < 2; ++kb)                \
    _Pragma("unroll") for (int mi = 0; mi < 4; ++mi)              \
      _Pragma("unroll") for (int nj = 0; nj < 2; ++nj)            \
        acc[(QM)*4+mi][(QN)*2+nj] = __builtin_amdgcn_mfma_f32_16x16x32_bf16( \
            aF[mi][kb], BF[nj][kb], acc[(QM)*4+mi][(QN)*2+nj], 0, 0, 0);     \
  __builtin_amdgcn_s_setprio(0);

  for (int it = 0; it < 36; ++it) {
    int t0 = 2 * it;
    const char* A0 = (const char*)As;
    const char* B0 = (const char*)Bs;
    const char* A1 = (const char*)As + 32768;
    const char* B1 = (const char*)Bs + 32768;
    // ---- ph1: Q00 of tile t0 ----
    LDA_HALF(A0, 0); LDB_HALF(B0, 0, b01);
    BAR(); MFMA_QUAD(b01, 0, 0); BAR();
    // ---- ph2: Q01 ----
    LDB_HALF(B0, 1, b23);
    BAR(); MFMA_QUAD(b23, 0, 1); BAR();
    // ---- ph3: Q10 ----
    LDA_HALF(A0, 1);
    stageB(t0 + 2, 0);
    BAR(); MFMA_QUAD(b01, 1, 0); BAR();
    // ---- ph4: Q11 ----
    stageB(t0 + 2, 1); stageA(t0 + 2, 0);
    BAR(); MFMA_QUAD(b23, 1, 1);
    if (it < 35) { asm volatile("s_waitcnt vmcnt(6)" ::: "memory"); }
    else         { asm volatile("s_waitcnt vmcnt(0)" ::: "memory"); }
    BAR();
    // ---- ph5: Q00 of tile t0+1 ----
    LDA_HALF(A1, 0); LDB_HALF(B1, 0, b01);
    stageA(t0 + 2, 1);
    BAR(); MFMA_QUAD(b01, 0, 0); BAR();
    // ---- ph6: Q01 ----
    LDB_HALF(B1, 1, b23);
    BAR(); MFMA_QUAD(b23, 0, 1); BAR();
    // ---- ph7: Q10 ----
    LDA_HALF(A1, 1);
    stageB(t0 + 3, 0);
    BAR(); MFMA_QUAD(b01, 1, 0); BAR();
    // ---- ph8: Q11 ----
    stageB(t0 + 3, 1); stageA(t0 + 3, 0); stageA(t0 + 3, 1);
    BAR(); MFMA_QUAD(b23, 1, 1);
    asm volatile("s_waitcnt vmcnt(8)" ::: "memory");
    BAR();
  }
#undef LDA_HALF
#undef LDB_HALF
#undef MFMA_QUAD

  // ---- epilogue: bias + relu -> feat[g][b][co*36+pix] (bf16) ----
  float bias[8][4];
  #pragma unroll
  for (int mi = 0; mi < 8; ++mi)
    #pragma unroll
    for (int r = 0; r < 4; ++r)
      bias[mi][r] = conv_b[g*512 + mt*256 + wr*128 + mi*16 + l4*4 + r];
  #pragma unroll
  for (int nj = 0; nj < 4; ++nj) {
    int n = nt*256 + wc*64 + nj*16 + l15;
    unsigned bb = (unsigned)n / 36u;
    unsigned pix = (unsigned)n % 36u;
    size_t base = ((size_t)g*B_ + bb)*FCK + pix;
    #pragma unroll
    for (int mi = 0; mi < 8; ++mi)
      #pragma unroll
      for (int r = 0; r < 4; ++r) {
        int m = mt*256 + wr*128 + mi*16 + l4*4 + r;
        float v = fmaxf(acc[mi][nj][r] + bias[mi][r], 0.f);
        feat[base + (size_t)m*36] = f2bf(v);
      }
  }
}

// ---------------- FC: per-group [128 x 18432] x [18432 x 160], split-K ----------------
__global__ void __launch_bounds__(256) k_fc(const u16* __restrict__ feat,
                                            const u16* __restrict__ wfcb,
                                            float* __restrict__ accum) {
  __shared__ __align__(16) u16 As[128*64];
  __shared__ __align__(16) u16 Bs[160*64];
  int sp = blockIdx.x;   // 0..15 k-split
  int g  = blockIdx.y;
  int tid = threadIdx.x;
  int lane = tid & 63, w = tid >> 6;
  int wr = w >> 1, wc = w & 1;
  int rl = lane >> 3, s = lane & 7;
  int l15 = lane & 15, l4 = lane >> 4;

  const u16* gA[4]; u16* lA[4];
  #pragma unroll
  for (int i = 0; i < 4; ++i) {
    int r = w*32 + i*8 + rl;
    int c = s ^ (r & 7);
    gA[i] = feat + ((size_t)g*B_ + r)*FCK + c*8;
    lA[i] = (u16*)As + (w*32 + i*8) * 64;
  }
  const u16* gB[5]; u16* lB[5];
  #pragma unroll
  for (int i = 0; i < 5; ++i) {
    int r = w*40 + i*8 + rl;
    int c = s ^ (r & 7);
    gB[i] = wfcb + ((size_t)(g*160 + r))*FCK + c*8;
    lB[i] = (u16*)Bs + (w*40 + i*8) * 64;
  }

  float4v acc[4][5];
  #pragma unroll
  for (int mi = 0; mi < 4; ++mi)
    #pragma unroll
    for (int nj = 0; nj < 5; ++nj) acc[mi][nj] = (float4v){0.f,0.f,0.f,0.f};

  size_t kbase = (size_t)sp * 1152;
  for (int stp = 0; stp < 18; ++stp) {
    size_t kofs = kbase + (size_t)stp * 64;
    __syncthreads();
    #pragma unroll
    for (int i = 0; i < 4; ++i) load_lds16(gA[i] + kofs, lA[i]);
    #pragma unroll
    for (int i = 0; i < 5; ++i) load_lds16(gB[i] + kofs, lB[i]);
    __syncthreads();

    short8 a[4][2], bf[5][2];
    #pragma unroll
    for (int kb = 0; kb < 2; ++kb) {
      #pragma unroll
      for (int mi = 0; mi < 4; ++mi) {
        int row = wr*64 + mi*16 + l15;
        int cb  = (kb*64 + l4*16) ^ ((row & 7) << 4);
        a[mi][kb] = *(const short8*)((const char*)As + row*128 + cb);
      }
      #pragma unroll
      for (int nj = 0; nj < 5; ++nj) {
        int row = wc*80 + nj*16 + l15;
        int cb  = (kb*64 + l4*16) ^ ((row & 7) << 4);
        bf[nj][kb] = *(const short8*)((const char*)Bs + row*128 + cb);
      }
    }
    #pragma unroll
    for (int kb = 0; kb < 2; ++kb)
      #pragma unroll
      for (int mi = 0; mi < 4; ++mi)
        #pragma unroll
        for (int nj = 0; nj < 5; ++nj)
          acc[mi][nj] = __builtin_amdgcn_mfma_f32_16x16x32_bf16(
              a[mi][kb], bf[nj][kb], acc[mi][nj], 0, 0, 0);
  }

  #pragma unroll
  for (int mi = 0; mi < 4; ++mi)
    #pragma unroll
    for (int r = 0; r < 4; ++r) {
      int brow = wr*64 + mi*16 + l4*4 + r;
      #pragma unroll
      for (int nj = 0; nj < 5; ++nj) {
        int o = wc*80 + nj*16 + l15;
        atomicAdd(&accum[((size_t)brow*20 + g)*160 + o], acc[mi][nj][r]);
      }
    }
}

__global__ void k_final(const float* __restrict__ accum, const float* __restrict__ fcb,
                        float* __restrict__ out) {
  int idx = blockIdx.x * 256 + threadIdx.x;     // 128*3000
  if (idx >= B_*3000) return;
  unsigned b = (unsigned)idx / 3000u;
  unsigned rem = (unsigned)idx % 3000u;
  unsigned g = rem / 150u, o = rem % 150u;
  out[idx] = fmaxf(accum[((size_t)b*20 + g)*160 + o] + fcb[g*150 + o], 0.f);
}

extern "C" void kernel_launch(void* const* d_in, const int* in_sizes, int n_in,
                              void* d_out, int out_size, void* d_ws, size_t ws_size,
                              hipStream_t stream) {
  const float* x      = (const float*)d_in[0];
  const float* y      = (const float*)d_in[1];
  const float* conv_w = (const float*)d_in[2];
  const float* conv_b = (const float*)d_in[3];
  const float* fc_w   = (const float*)d_in[4];
  const float* fc_b   = (const float*)d_in[5];
  float* out = (float*)d_out;

  char* ws = (char*)d_ws;
  size_t off = 0;
  u16* Wb   = (u16*)(ws + off); off += (size_t)10240 * K2 * 2;        // 94.4 MB
  u16* up3  = (u16*)(ws + off); off += (size_t)G_ * B_ * 64 * C_ * 2; // 167.8 MB
  u16* feat = (u16*)(ws + off); off += (size_t)G_ * B_ * FCK * 2;     // 94.4 MB
  float* accum = (float*)(ws + off); off += (size_t)B_ * G_ * 160 * 4;// 1.6 MB
  int* cx = (int*)(ws + off); off += B_ * G_ * 4;
  int* cy = (int*)(ws + off); off += B_ * G_ * 4;
  u16* Wfcb = up3;   // alias: fc weights built AFTER conv consumed up3 (peak ws 358 MB)

  k_pos<<<1, 128, 0, stream>>>(y, cx, cy);
  k_convw<<<(10240*512)/256, 256, 0, stream>>>(conv_w, Wb);
  k_up3<<<B_*G_, 256, 0, stream>>>(x, cx, cy, up3);
  hipMemsetAsync(accum, 0, (size_t)B_ * G_ * 160 * 4, stream);
  k_conv<<<720, 512, 0, stream>>>(Wb, up3, conv_b, feat);
  k_fcw<<<dim3(144, 20), 256, 0, stream>>>(fc_w, Wfcb);
  k_fc<<<dim3(16, 20), 256, 0, stream>>>(feat, Wfcb, accum);
  k_final<<<(B_*3000 + 255)/256, 256, 0, stream>>>(accum, fc_b, out);
}

// Round 7
// 615.771 us; speedup vs baseline: 1.1628x; 1.0216x over previous
//
#include <hip/hip_runtime.h>
#include <stdint.h>

#define B_  128
#define C_  512
#define G_  20
#define K2  4608      // C_*9, conv GEMM K
#define FCK 18432     // C_*36, fc GEMM K

typedef unsigned short u16;
typedef unsigned int   u32;
typedef __attribute__((ext_vector_type(8))) short  short8;
typedef __attribute__((ext_vector_type(4))) short  short4v;
typedef __attribute__((ext_vector_type(4))) float  float4v;

__device__ __forceinline__ u16 f2bf(float f) {
  u32 u = __builtin_bit_cast(u32, f);
  u = (u + 0x7fffu + ((u >> 16) & 1u)) >> 16;   // RNE
  return (u16)u;
}

__device__ __forceinline__ void load_lds16(const void* g, void* l) {
  __builtin_amdgcn_global_load_lds(
      (const __attribute__((address_space(1))) void*)(uintptr_t)g,
      (__attribute__((address_space(3))) void*)(uint32_t)(uintptr_t)l,
      16, 0, 0);
}

#define BAR() __builtin_amdgcn_s_barrier()

// ---------------- landmarks -> integer crop positions ----------------
__global__ void k_pos(const float* __restrict__ y, int* __restrict__ cx, int* __restrict__ cy) {
  int b = blockIdx.x * blockDim.x + threadIdx.x;
  if (b >= B_) return;
  const int   I1[10] = {21,18,19,41,38,49,48,51,61,56};
  const int   I2[10] = {22,25,24,46,43,53,54,57,63,58};
  const float CF[10] = {-0.5f, -1.0f/3.0f, 1.0f/3.0f, 1.0f, 0.f,0.f,0.f,0.f,0.f, 0.5f};
  const float* yb = y + b * 136;
  float ruler = fabsf(yb[2*39] - yb[2*42]);
  for (int j = 0; j < 10; ++j) {
    float off = ruler * CF[j];
    float vx1 = yb[2*I1[j]];
    float vy1 = yb[2*I1[j]+1] + off;
    float vx2 = yb[2*I2[j]];
    float vy2 = yb[2*I2[j]+1] + off;
    int px1 = (int)(vx1 * 0.0625f); px1 = min(max(px1,1),12);
    int py1 = (int)(vy1 * 0.0625f); py1 = min(max(py1,1),12);
    int px2 = (int)(vx2 * 0.0625f); px2 = min(max(px2,1),12);
    int py2 = (int)(vy2 * 0.0625f); py2 = min(max(py2,1),12);
    cx[b*20 + 2*j]   = px1;  cx[b*20 + 2*j+1] = px2;
    cy[b*20 + 2*j]   = py1;  cy[b*20 + 2*j+1] = py2;
  }
}

// ------------- conv_w f32 [o][ci][t] -> bf16 Wb[o][t*512+ci] -------------
// v2: float4-coalesced reads (4 o-panels of 4608 consecutive floats) -> LDS,
// then short8-coalesced transposed writes (perfect store coalescing; the
// stride-9 LDS gather's 8-way conflict is far below the HBM cost).
__global__ void __launch_bounds__(256) k_convw(const float* __restrict__ w, u16* __restrict__ wb) {
  __shared__ u16 lds[4 * 4608];                   // 36.9 KB
  int ob = blockIdx.x * 4;                        // 2560 blocks
  int tid = threadIdx.x;
  const float4* in4 = (const float4*)(w + (size_t)ob * 4608);
  #pragma unroll
  for (int r = 0; r < 18; ++r) {
    int fi = r * 256 + tid;                       // 0..4607 float4s
    float4 v = in4[fi];
    u16 q[4] = { f2bf(v.x), f2bf(v.y), f2bf(v.z), f2bf(v.w) };
    *(short4v*)&lds[fi * 4] = *(short4v*)q;
  }
  __syncthreads();
  #pragma unroll
  for (int r = 0; r < 9; ++r) {
    int wi = r * 256 + tid;                       // 0..2303 = 4o x 9t x 64ci8
    int ci0 = (wi & 63) * 8;
    int t   = (wi >> 6) % 9;
    int o   = wi / 576;
    u16 vals[8];
    #pragma unroll
    for (int j = 0; j < 8; ++j) vals[j] = lds[o * 4608 + (ci0 + j) * 9 + t];
    *(short8*)(wb + ((size_t)(ob + o)) * K2 + t * 512 + ci0) = *(short8*)vals;
  }
}

// ------- crop + bilinear 2x upsample -> up3[g][b][pp(8x8 pad)][ci] bf16 -------
__global__ void __launch_bounds__(256) k_up3(const float* __restrict__ x,
                                             const int* __restrict__ cx,
                                             const int* __restrict__ cy,
                                             u16* __restrict__ up3) {
  __shared__ float crop[3][3][C_];   // [r][s][ci]
  int bg = blockIdx.x;               // b*20+g
  int b = bg / 20, g = bg % 20;
  int X = cx[bg] - 1, Y = cy[bg] - 1;
  const float* xb = x + (size_t)b * (C_*14*14);
  int t = threadIdx.x;
  for (int it = 0; it < 6; ++it) {
    int idx = it*256 + t;            // 1536 = 512*3
    int r = idx >> 9, ci = idx & 511;
    const float* srow = xb + ci*196 + (Y + r)*14 + X;
    crop[r][0][ci] = srow[0];
    crop[r][1][ci] = srow[1];
    crop[r][2][ci] = srow[2];
  }
  __syncthreads();
  const int   R0[6] = {0,0,0,1,1,1};
  const float WA[6] = {1.f, .75f, .25f, .75f, .25f, 0.f};
  u16* dstbase = up3 + ((size_t)g*B_ + b) * 64 * C_;
  for (int it = 0; it < 16; ++it) {
    int cidx = it*256 + t;           // 4096 chunks of 8 ci
    int pp = cidx >> 6;
    int c8 = (cidx & 63) * 8;
    int ph = pp >> 3, pw = pp & 7;
    u16 outv[8];
    if (ph == 0 || ph == 7 || pw == 0 || pw == 7) {
      #pragma unroll
      for (int j = 0; j < 8; ++j) outv[j] = 0;
    } else {
      int oh = ph - 1, ow = pw - 1;
      int r0 = R0[oh]; float wy0 = WA[oh], wy1 = 1.f - WA[oh];
      int s0 = R0[ow]; float wx0 = WA[ow], wx1 = 1.f - WA[ow];
      #pragma unroll
      for (int j = 0; j < 8; ++j) {
        int ci = c8 + j;
        float v = wy0*(wx0*crop[r0][s0][ci]   + wx1*crop[r0][s0+1][ci])
                + wy1*(wx0*crop[r0+1][s0][ci] + wx1*crop[r0+1][s0+1][ci]);
        outv[j] = f2bf(v);
      }
    }
    *(short8*)(dstbase + (size_t)pp*C_ + c8) = *(short8*)outv;
  }
}

// ---------------- grouped conv as implicit GEMM, 8-phase template ----------------
// (unchanged from round 6)
__global__ void __launch_bounds__(512, 2) k_conv(const u16* __restrict__ wb,
                                                 const u16* __restrict__ up3,
                                                 const float* __restrict__ conv_b,
                                                 u16* __restrict__ feat) {
  __shared__ __align__(16) u16 As[2 * 256 * 64];   // 64 KB (2 dbuf)
  __shared__ __align__(16) u16 Bs[2 * 256 * 64];   // 64 KB
  int bid = blockIdx.x;
  int lid = (bid & 7) * 90 + (bid >> 3);    // bijective: 720 = 8*90
  int mt = lid & 1;                          // innermost: B-tile reuse pair
  int nt = (lid >> 1) % 18;
  int g  = lid / 36;
  int tid = threadIdx.x;
  int lane = tid & 63;
  int w = tid >> 6;                          // 8 waves
  int wr = w >> 2, wc = w & 3;               // 2M x 4N
  int l15 = lane & 15, l4 = lane >> 4;

  int rl0 = tid >> 3, sl0 = tid & 7;
  const u16* srcA0 = wb + (size_t)(g*512 + mt*256 + rl0) * K2 + (sl0 ^ (rl0 & 7)) * 8;
  const u16* srcB[2][2];
  #pragma unroll
  for (int h = 0; h < 2; ++h)
    #pragma unroll
    for (int j = 0; j < 2; ++j) {
      int rl = j * 64 + rl0;                 // within half: 0..127
      int n  = nt * 256 + h * 128 + rl;
      unsigned bb = (unsigned)n / 36u;
      unsigned pix = (unsigned)n % 36u;
      int pixA = (int)(pix / 6u) * 8 + (int)(pix % 6u);
      srcB[h][j] = up3 + (((size_t)g*B_ + bb)*64 + pixA) * C_ + (sl0 ^ (rl0 & 7)) * 8;
    }

  auto stageA = [&](int st, int h) {
    if (st >= 72) return;
    int db = st & 1;
    size_t ko = (size_t)st * 64;
    #pragma unroll
    for (int j = 0; j < 2; ++j)
      load_lds16(srcA0 + (size_t)(h*128 + j*64) * K2 + ko,
                 (char*)As + db*32768 + h*16384 + (j*512 + tid)*16);
  };
  auto stageB = [&](int st, int h) {
    if (st >= 72) return;
    int db = st & 1;
    int t9 = st >> 3;
    size_t ko = (size_t)((t9/3)*8 + (t9%3)) * C_ + (size_t)(st & 7) * 64;
    #pragma unroll
    for (int j = 0; j < 2; ++j)
      load_lds16(srcB[h][j] + ko,
                 (char*)Bs + db*32768 + h*16384 + (j*512 + tid)*16);
  };

  auto ldfrag = [&](const char* base, int row, int kb) -> short8 {
    int cb = (kb*64 + l4*16) ^ ((row & 7) << 4);
    return *(const short8*)(base + row*128 + cb);
  };

  float4v acc[8][4];
  #pragma unroll
  for (int mi = 0; mi < 8; ++mi)
    #pragma unroll
    for (int nj = 0; nj < 4; ++nj) acc[mi][nj] = (float4v){0.f,0.f,0.f,0.f};

  stageB(0,0); stageB(0,1); stageA(0,0); stageA(0,1);
  stageB(1,0); stageB(1,1); stageA(1,0); stageA(1,1);
  asm volatile("s_waitcnt vmcnt(8)" ::: "memory");
  BAR();

  short8 aF[4][2], b01[2][2], b23[2][2];

#define LDA_HALF(BASE, MH)                                        \
  _Pragma("unroll") for (int mi = 0; mi < 4; ++mi)                \
    _Pragma("unroll") for (int kb = 0; kb < 2; ++kb)              \
      aF[mi][kb] = ldfrag(BASE, wr*128 + ((MH)*4 + mi)*16 + l15, kb);
#define LDB_HALF(BASE, NH, DST)                                   \
  _Pragma("unroll") for (int nj = 0; nj < 2; ++nj)                \
    _Pragma("unroll") for (int kb = 0; kb < 2; ++kb)              \
      DST[nj][kb] = ldfrag(BASE, wc*64 + ((NH)*2 + nj)*16 + l15, kb);
#define MFMA_QUAD(BF, QM, QN)                                     \
  __builtin_amdgcn_s_setprio(1);                                  \
  _Pragma("unroll") for (int kb = 0; kb < 2; ++kb)                \
    _Pragma("unroll") for (int mi = 0; mi < 4; ++mi)              \
      _Pragma("unroll") for (int nj = 0; nj < 2; ++nj)            \
        acc[(QM)*4+mi][(QN)*2+nj] = __builtin_amdgcn_mfma_f32_16x16x32_bf16( \
            aF[mi][kb], BF[nj][kb], acc[(QM)*4+mi][(QN)*2+nj], 0, 0, 0);     \
  __builtin_amdgcn_s_setprio(0);

  for (int it = 0; it < 36; ++it) {
    int t0 = 2 * it;
    const char* A0 = (const char*)As;
    const char* B0 = (const char*)Bs;
    const char* A1 = (const char*)As + 32768;
    const char* B1 = (const char*)Bs + 32768;
    // ---- ph1 ----
    LDA_HALF(A0, 0); LDB_HALF(B0, 0, b01);
    BAR(); MFMA_QUAD(b01, 0, 0); BAR();
    // ---- ph2 ----
    LDB_HALF(B0, 1, b23);
    BAR(); MFMA_QUAD(b23, 0, 1); BAR();
    // ---- ph3 ----
    LDA_HALF(A0, 1);
    stageB(t0 + 2, 0);
    BAR(); MFMA_QUAD(b01, 1, 0); BAR();
    // ---- ph4 ----
    stageB(t0 + 2, 1); stageA(t0 + 2, 0);
    BAR(); MFMA_QUAD(b23, 1, 1);
    if (it < 35) { asm volatile("s_waitcnt vmcnt(6)" ::: "memory"); }
    else         { asm volatile("s_waitcnt vmcnt(0)" ::: "memory"); }
    BAR();
    // ---- ph5 ----
    LDA_HALF(A1, 0); LDB_HALF(B1, 0, b01);
    stageA(t0 + 2, 1);
    BAR(); MFMA_QUAD(b01, 0, 0); BAR();
    // ---- ph6 ----
    LDB_HALF(B1, 1, b23);
    BAR(); MFMA_QUAD(b23, 0, 1); BAR();
    // ---- ph7 ----
    LDA_HALF(A1, 1);
    stageB(t0 + 3, 0);
    BAR(); MFMA_QUAD(b01, 1, 0); BAR();
    // ---- ph8 ----
    stageB(t0 + 3, 1); stageA(t0 + 3, 0); stageA(t0 + 3, 1);
    BAR(); MFMA_QUAD(b23, 1, 1);
    asm volatile("s_waitcnt vmcnt(8)" ::: "memory");
    BAR();
  }
#undef LDA_HALF
#undef LDB_HALF
#undef MFMA_QUAD

  float bias[8][4];
  #pragma unroll
  for (int mi = 0; mi < 8; ++mi)
    #pragma unroll
    for (int r = 0; r < 4; ++r)
      bias[mi][r] = conv_b[g*512 + mt*256 + wr*128 + mi*16 + l4*4 + r];
  #pragma unroll
  for (int nj = 0; nj < 4; ++nj) {
    int n = nt*256 + wc*64 + nj*16 + l15;
    unsigned bb = (unsigned)n / 36u;
    unsigned pix = (unsigned)n % 36u;
    size_t base = ((size_t)g*B_ + bb)*FCK + pix;
    #pragma unroll
    for (int mi = 0; mi < 8; ++mi)
      #pragma unroll
      for (int r = 0; r < 4; ++r) {
        int m = mt*256 + wr*128 + mi*16 + l4*4 + r;
        float v = fmaxf(acc[mi][nj][r] + bias[mi][r], 0.f);
        feat[base + (size_t)m*36] = f2bf(v);
      }
  }
}

// ---------------- FC fused: per-group [128 x 18432] x f32 fc_w -> accum ----------------
// B staged directly from f32 fc_w: coalesced stride-150 loads (lanes =
// consecutive o), in-register f2bf, ds_write_b128 into the SAME XOR-swizzled
// Bs layout the MFMA fragment reads use (write slot il8^(o&7) == read slot
// (kb*4+l4)^(o&7); both-sides swizzle). Split-K 32 (640 blocks, 9 K-steps).
// Kills the k_fcw round-trip (472 MB of HBM).
__global__ void __launch_bounds__(256) k_fc(const u16* __restrict__ feat,
                                            const float* __restrict__ fw,
                                            float* __restrict__ accum) {
  __shared__ __align__(16) u16 As[128*64];   // 16 KB
  __shared__ __align__(16) u16 Bs[160*64];   // 20 KB
  int sp = blockIdx.x;   // 0..31 k-split
  int g  = blockIdx.y;
  int tid = threadIdx.x;
  int lane = tid & 63, w = tid >> 6;
  int wr = w >> 1, wc = w & 1;
  int rl = lane >> 3, s = lane & 7;
  int l15 = lane & 15, l4 = lane >> 4;

  const u16* gA[4]; u16* lA[4];
  #pragma unroll
  for (int i = 0; i < 4; ++i) {
    int r = w*32 + i*8 + rl;
    int c = s ^ (r & 7);
    gA[i] = feat + ((size_t)g*B_ + r)*FCK + c*8;
    lA[i] = (u16*)As + (w*32 + i*8) * 64;
  }

  float4v acc[4][5];
  #pragma unroll
  for (int mi = 0; mi < 4; ++mi)
    #pragma unroll
    for (int nj = 0; nj < 5; ++nj) acc[mi][nj] = (float4v){0.f,0.f,0.f,0.f};

  int kbase = sp * 576;
  for (int stp = 0; stp < 9; ++stp) {
    int i0 = kbase + stp * 64;
    __syncthreads();
    #pragma unroll
    for (int i = 0; i < 4; ++i) load_lds16(gA[i] + i0, lA[i]);
    // ---- B stage: 1280 (il8, o) items over 5 iterations ----
    #pragma unroll
    for (int bit = 0; bit < 5; ++bit) {
      int idx = bit * 256 + tid;
      int il8 = idx / 160;           // k-slot 0..7
      int o   = idx - il8 * 160;     // 0..159
      u16 vals[8];
      if (o < 150) {
        const float* src = fw + ((size_t)g * FCK + i0 + il8 * 8) * 150 + o;
        #pragma unroll
        for (int j = 0; j < 8; ++j) vals[j] = f2bf(src[(size_t)j * 150]);
      } else {
        #pragma unroll
        for (int j = 0; j < 8; ++j) vals[j] = 0;
      }
      *(short8*)((char*)Bs + o * 128 + ((il8 ^ (o & 7)) * 16)) = *(short8*)vals;
    }
    __syncthreads();

    short8 a[4][2], bf[5][2];
    #pragma unroll
    for (int kb = 0; kb < 2; ++kb) {
      #pragma unroll
      for (int mi = 0; mi < 4; ++mi) {
        int row = wr*64 + mi*16 + l15;
        int cb  = (kb*64 + l4*16) ^ ((row & 7) << 4);
        a[mi][kb] = *(const short8*)((const char*)As + row*128 + cb);
      }
      #pragma unroll
      for (int nj = 0; nj < 5; ++nj) {
        int row = wc*80 + nj*16 + l15;
        int cb  = (kb*64 + l4*16) ^ ((row & 7) << 4);
        bf[nj][kb] = *(const short8*)((const char*)Bs + row*128 + cb);
      }
    }
    #pragma unroll
    for (int kb = 0; kb < 2; ++kb)
      #pragma unroll
      for (int mi = 0; mi < 4; ++mi)
        #pragma unroll
        for (int nj = 0; nj < 5; ++nj)
          acc[mi][nj] = __builtin_amdgcn_mfma_f32_16x16x32_bf16(
              a[mi][kb], bf[nj][kb], acc[mi][nj], 0, 0, 0);
  }

  #pragma unroll
  for (int mi = 0; mi < 4; ++mi)
    #pragma unroll
    for (int r = 0; r < 4; ++r) {
      int brow = wr*64 + mi*16 + l4*4 + r;
      #pragma unroll
      for (int nj = 0; nj < 5; ++nj) {
        int o = wc*80 + nj*16 + l15;
        atomicAdd(&accum[((size_t)brow*20 + g)*160 + o], acc[mi][nj][r]);
      }
    }
}

__global__ void k_final(const float* __restrict__ accum, const float* __restrict__ fcb,
                        float* __restrict__ out) {
  int idx = blockIdx.x * 256 + threadIdx.x;     // 128*3000
  if (idx >= B_*3000) return;
  unsigned b = (unsigned)idx / 3000u;
  unsigned rem = (unsigned)idx % 3000u;
  unsigned g = rem / 150u, o = rem % 150u;
  out[idx] = fmaxf(accum[((size_t)b*20 + g)*160 + o] + fcb[g*150 + o], 0.f);
}

extern "C" void kernel_launch(void* const* d_in, const int* in_sizes, int n_in,
                              void* d_out, int out_size, void* d_ws, size_t ws_size,
                              hipStream_t stream) {
  const float* x      = (const float*)d_in[0];
  const float* y      = (const float*)d_in[1];
  const float* conv_w = (const float*)d_in[2];
  const float* conv_b = (const float*)d_in[3];
  const float* fc_w   = (const float*)d_in[4];
  const float* fc_b   = (const float*)d_in[5];
  float* out = (float*)d_out;

  char* ws = (char*)d_ws;
  size_t off = 0;
  u16* Wb   = (u16*)(ws + off); off += (size_t)10240 * K2 * 2;        // 94.4 MB
  u16* up3  = (u16*)(ws + off); off += (size_t)G_ * B_ * 64 * C_ * 2; // 167.8 MB
  u16* feat = (u16*)(ws + off); off += (size_t)G_ * B_ * FCK * 2;     // 94.4 MB
  float* accum = (float*)(ws + off); off += (size_t)B_ * G_ * 160 * 4;// 1.6 MB
  int* cx = (int*)(ws + off); off += B_ * G_ * 4;
  int* cy = (int*)(ws + off); off += B_ * G_ * 4;

  k_pos<<<1, 128, 0, stream>>>(y, cx, cy);
  k_convw<<<2560, 256, 0, stream>>>(conv_w, Wb);
  k_up3<<<B_*G_, 256, 0, stream>>>(x, cx, cy, up3);
  hipMemsetAsync(accum, 0, (size_t)B_ * G_ * 160 * 4, stream);
  k_conv<<<720, 512, 0, stream>>>(Wb, up3, conv_b, feat);
  k_fc<<<dim3(32, 20), 256, 0, stream>>>(feat, fc_w, accum);
  k_final<<<(B_*3000 + 255)/256, 256, 0, stream>>>(accum, fc_b, out);
}

// Round 8
// 603.609 us; speedup vs baseline: 1.1862x; 1.0201x over previous
//
#include <hip/hip_runtime.h>
#include <stdint.h>

#define B_  128
#define C_  512
#define G_  20
#define K2  4608      // C_*9, conv GEMM K
#define FCK 18432     // C_*36, fc GEMM K

typedef unsigned short u16;
typedef unsigned int   u32;
typedef __attribute__((ext_vector_type(8))) short  short8;
typedef __attribute__((ext_vector_type(4))) short  short4v;
typedef __attribute__((ext_vector_type(4))) float  float4v;

__device__ __forceinline__ u16 f2bf(float f) {
  u32 u = __builtin_bit_cast(u32, f);
  u = (u + 0x7fffu + ((u >> 16) & 1u)) >> 16;   // RNE
  return (u16)u;
}

__device__ __forceinline__ void load_lds16(const void* g, void* l) {
  __builtin_amdgcn_global_load_lds(
      (const __attribute__((address_space(1))) void*)(uintptr_t)g,
      (__attribute__((address_space(3))) void*)(uint32_t)(uintptr_t)l,
      16, 0, 0);
}

#define BAR() __builtin_amdgcn_s_barrier()

// ---------------- landmarks -> integer crop positions ----------------
__global__ void k_pos(const float* __restrict__ y, int* __restrict__ cx, int* __restrict__ cy) {
  int b = blockIdx.x * blockDim.x + threadIdx.x;
  if (b >= B_) return;
  const int   I1[10] = {21,18,19,41,38,49,48,51,61,56};
  const int   I2[10] = {22,25,24,46,43,53,54,57,63,58};
  const float CF[10] = {-0.5f, -1.0f/3.0f, 1.0f/3.0f, 1.0f, 0.f,0.f,0.f,0.f,0.f, 0.5f};
  const float* yb = y + b * 136;
  float ruler = fabsf(yb[2*39] - yb[2*42]);
  for (int j = 0; j < 10; ++j) {
    float off = ruler * CF[j];
    float vx1 = yb[2*I1[j]];
    float vy1 = yb[2*I1[j]+1] + off;
    float vx2 = yb[2*I2[j]];
    float vy2 = yb[2*I2[j]+1] + off;
    int px1 = (int)(vx1 * 0.0625f); px1 = min(max(px1,1),12);
    int py1 = (int)(vy1 * 0.0625f); py1 = min(max(py1,1),12);
    int px2 = (int)(vx2 * 0.0625f); px2 = min(max(px2,1),12);
    int py2 = (int)(vy2 * 0.0625f); py2 = min(max(py2,1),12);
    cx[b*20 + 2*j]   = px1;  cx[b*20 + 2*j+1] = px2;
    cy[b*20 + 2*j]   = py1;  cy[b*20 + 2*j+1] = py2;
  }
}

// ---------------- fused pre-pass: conv_w convert + crop/upsample ----------------
// blocks [0,2560): conv_w f32 [o][ci][t] -> bf16 Wb[o][t*512+ci] (4 o per block)
// blocks [2560,5120): crop+bilinear -> up3[g][b][pp(8x8 pad)][ci] bf16
// Independent inputs; fused so the two BW-bound passes overlap on the device.
__global__ void __launch_bounds__(256) k_pre(const float* __restrict__ w, u16* __restrict__ wb,
                                             const float* __restrict__ x,
                                             const int* __restrict__ cx, const int* __restrict__ cy,
                                             u16* __restrict__ up3) {
  __shared__ __align__(16) char smraw[4 * 4608 * 2];   // 36.9 KB, shared by both paths
  int tid = threadIdx.x;
  if (blockIdx.x < 2560) {
    u16* lds = (u16*)smraw;
    int ob = blockIdx.x * 4;
    const float4* in4 = (const float4*)(w + (size_t)ob * 4608);
    #pragma unroll
    for (int r = 0; r < 18; ++r) {
      int fi = r * 256 + tid;                       // 0..4607 float4s
      float4 v = in4[fi];
      u16 q[4] = { f2bf(v.x), f2bf(v.y), f2bf(v.z), f2bf(v.w) };
      *(short4v*)&lds[fi * 4] = *(short4v*)q;
    }
    __syncthreads();
    #pragma unroll
    for (int r = 0; r < 9; ++r) {
      int wi = r * 256 + tid;                       // 0..2303 = 4o x 9t x 64ci8
      int ci0 = (wi & 63) * 8;
      int t   = (wi >> 6) % 9;
      int o   = wi / 576;
      u16 vals[8];
      #pragma unroll
      for (int j = 0; j < 8; ++j) vals[j] = lds[o * 4608 + (ci0 + j) * 9 + t];
      *(short8*)(wb + ((size_t)(ob + o)) * K2 + t * 512 + ci0) = *(short8*)vals;
    }
  } else {
    float (*crop)[3][C_] = (float(*)[3][C_])smraw;   // [r][s][ci], 18.4 KB
    int bg = blockIdx.x - 2560;        // b*20+g
    int b = bg / 20, g = bg % 20;
    int X = cx[bg] - 1, Y = cy[bg] - 1;
    const float* xb = x + (size_t)b * (C_*14*14);
    for (int it = 0; it < 6; ++it) {
      int idx = it*256 + tid;          // 1536 = 512*3
      int r = idx >> 9, ci = idx & 511;
      const float* srow = xb + ci*196 + (Y + r)*14 + X;
      crop[r][0][ci] = srow[0];
      crop[r][1][ci] = srow[1];
      crop[r][2][ci] = srow[2];
    }
    __syncthreads();
    const int   R0[6] = {0,0,0,1,1,1};
    const float WA[6] = {1.f, .75f, .25f, .75f, .25f, 0.f};
    u16* dstbase = up3 + ((size_t)g*B_ + b) * 64 * C_;
    for (int it = 0; it < 16; ++it) {
      int cidx = it*256 + tid;         // 4096 chunks of 8 ci
      int pp = cidx >> 6;
      int c8 = (cidx & 63) * 8;
      int ph = pp >> 3, pw = pp & 7;
      u16 outv[8];
      if (ph == 0 || ph == 7 || pw == 0 || pw == 7) {
        #pragma unroll
        for (int j = 0; j < 8; ++j) outv[j] = 0;
      } else {
        int oh = ph - 1, ow = pw - 1;
        int r0 = R0[oh]; float wy0 = WA[oh], wy1 = 1.f - WA[oh];
        int s0 = R0[ow]; float wx0 = WA[ow], wx1 = 1.f - WA[ow];
        #pragma unroll
        for (int j = 0; j < 8; ++j) {
          int ci = c8 + j;
          float v = wy0*(wx0*crop[r0][s0][ci]   + wx1*crop[r0][s0+1][ci])
                  + wy1*(wx0*crop[r0+1][s0][ci] + wx1*crop[r0+1][s0+1][ci]);
          outv[j] = f2bf(v);
        }
      }
      *(short8*)(dstbase + (size_t)pp*C_ + c8) = *(short8*)outv;
    }
  }
}

// ---------------- grouped conv as implicit GEMM, 8-phase template ----------------
// Inner loop unchanged from round 6. Epilogue now writes feat in layout
// feat[g][b][pix*512+co] (k-index i' = pix*512+co): lane holds 4 consecutive
// co -> one short4 (8B) store per (mi,nj) instead of 4 stride-36 u16 stores.
__global__ void __launch_bounds__(512, 2) k_conv(const u16* __restrict__ wb,
                                                 const u16* __restrict__ up3,
                                                 const float* __restrict__ conv_b,
                                                 u16* __restrict__ feat) {
  __shared__ __align__(16) u16 As[2 * 256 * 64];   // 64 KB (2 dbuf)
  __shared__ __align__(16) u16 Bs[2 * 256 * 64];   // 64 KB
  int bid = blockIdx.x;
  int lid = (bid & 7) * 90 + (bid >> 3);    // bijective: 720 = 8*90
  int mt = lid & 1;                          // innermost: B-tile reuse pair
  int nt = (lid >> 1) % 18;
  int g  = lid / 36;
  int tid = threadIdx.x;
  int lane = tid & 63;
  int w = tid >> 6;                          // 8 waves
  int wr = w >> 2, wc = w & 3;               // 2M x 4N
  int l15 = lane & 15, l4 = lane >> 4;

  int rl0 = tid >> 3, sl0 = tid & 7;
  const u16* srcA0 = wb + (size_t)(g*512 + mt*256 + rl0) * K2 + (sl0 ^ (rl0 & 7)) * 8;
  const u16* srcB[2][2];
  #pragma unroll
  for (int h = 0; h < 2; ++h)
    #pragma unroll
    for (int j = 0; j < 2; ++j) {
      int rl = j * 64 + rl0;                 // within half: 0..127
      int n  = nt * 256 + h * 128 + rl;
      unsigned bb = (unsigned)n / 36u;
      unsigned pix = (unsigned)n % 36u;
      int pixA = (int)(pix / 6u) * 8 + (int)(pix % 6u);
      srcB[h][j] = up3 + (((size_t)g*B_ + bb)*64 + pixA) * C_ + (sl0 ^ (rl0 & 7)) * 8;
    }

  auto stageA = [&](int st, int h) {
    if (st >= 72) return;
    int db = st & 1;
    size_t ko = (size_t)st * 64;
    #pragma unroll
    for (int j = 0; j < 2; ++j)
      load_lds16(srcA0 + (size_t)(h*128 + j*64) * K2 + ko,
                 (char*)As + db*32768 + h*16384 + (j*512 + tid)*16);
  };
  auto stageB = [&](int st, int h) {
    if (st >= 72) return;
    int db = st & 1;
    int t9 = st >> 3;
    size_t ko = (size_t)((t9/3)*8 + (t9%3)) * C_ + (size_t)(st & 7) * 64;
    #pragma unroll
    for (int j = 0; j < 2; ++j)
      load_lds16(srcB[h][j] + ko,
                 (char*)Bs + db*32768 + h*16384 + (j*512 + tid)*16);
  };

  auto ldfrag = [&](const char* base, int row, int kb) -> short8 {
    int cb = (kb*64 + l4*16) ^ ((row & 7) << 4);
    return *(const short8*)(base + row*128 + cb);
  };

  float4v acc[8][4];
  #pragma unroll
  for (int mi = 0; mi < 8; ++mi)
    #pragma unroll
    for (int nj = 0; nj < 4; ++nj) acc[mi][nj] = (float4v){0.f,0.f,0.f,0.f};

  stageB(0,0); stageB(0,1); stageA(0,0); stageA(0,1);
  stageB(1,0); stageB(1,1); stageA(1,0); stageA(1,1);
  asm volatile("s_waitcnt vmcnt(8)" ::: "memory");
  BAR();

  short8 aF[4][2], b01[2][2], b23[2][2];

#define LDA_HALF(BASE, MH)                                        \
  _Pragma("unroll") for (int mi = 0; mi < 4; ++mi)                \
    _Pragma("unroll") for (int kb = 0; kb < 2; ++kb)              \
      aF[mi][kb] = ldfrag(BASE, wr*128 + ((MH)*4 + mi)*16 + l15, kb);
#define LDB_HALF(BASE, NH, DST)                                   \
  _Pragma("unroll") for (int nj = 0; nj < 2; ++nj)                \
    _Pragma("unroll") for (int kb = 0; kb < 2; ++kb)              \
      DST[nj][kb] = ldfrag(BASE, wc*64 + ((NH)*2 + nj)*16 + l15, kb);
#define MFMA_QUAD(BF, QM, QN)                                     \
  __builtin_amdgcn_s_setprio(1);                                  \
  _Pragma("unroll") for (int kb = 0; kb < 2; ++kb)                \
    _Pragma("unroll") for (int mi = 0; mi < 4; ++mi)              \
      _Pragma("unroll") for (int nj = 0; nj < 2; ++nj)            \
        acc[(QM)*4+mi][(QN)*2+nj] = __builtin_amdgcn_mfma_f32_16x16x32_bf16( \
            aF[mi][kb], BF[nj][kb], acc[(QM)*4+mi][(QN)*2+nj], 0, 0, 0);     \
  __builtin_amdgcn_s_setprio(0);

  for (int it = 0; it < 36; ++it) {
    int t0 = 2 * it;
    const char* A0 = (const char*)As;
    const char* B0 = (const char*)Bs;
    const char* A1 = (const char*)As + 32768;
    const char* B1 = (const char*)Bs + 32768;
    // ---- ph1 ----
    LDA_HALF(A0, 0); LDB_HALF(B0, 0, b01);
    BAR(); MFMA_QUAD(b01, 0, 0); BAR();
    // ---- ph2 ----
    LDB_HALF(B0, 1, b23);
    BAR(); MFMA_QUAD(b23, 0, 1); BAR();
    // ---- ph3 ----
    LDA_HALF(A0, 1);
    stageB(t0 + 2, 0);
    BAR(); MFMA_QUAD(b01, 1, 0); BAR();
    // ---- ph4 ----
    stageB(t0 + 2, 1); stageA(t0 + 2, 0);
    BAR(); MFMA_QUAD(b23, 1, 1);
    if (it < 35) { asm volatile("s_waitcnt vmcnt(6)" ::: "memory"); }
    else         { asm volatile("s_waitcnt vmcnt(0)" ::: "memory"); }
    BAR();
    // ---- ph5 ----
    LDA_HALF(A1, 0); LDB_HALF(B1, 0, b01);
    stageA(t0 + 2, 1);
    BAR(); MFMA_QUAD(b01, 0, 0); BAR();
    // ---- ph6 ----
    LDB_HALF(B1, 1, b23);
    BAR(); MFMA_QUAD(b23, 0, 1); BAR();
    // ---- ph7 ----
    LDA_HALF(A1, 1);
    stageB(t0 + 3, 0);
    BAR(); MFMA_QUAD(b01, 1, 0); BAR();
    // ---- ph8 ----
    stageB(t0 + 3, 1); stageA(t0 + 3, 0); stageA(t0 + 3, 1);
    BAR(); MFMA_QUAD(b23, 1, 1);
    asm volatile("s_waitcnt vmcnt(8)" ::: "memory");
    BAR();
  }
#undef LDA_HALF
#undef LDB_HALF
#undef MFMA_QUAD

  // ---- epilogue: bias + relu -> feat[g][b][pix*512+co], short4 stores ----
  float bias[8][4];
  #pragma unroll
  for (int mi = 0; mi < 8; ++mi)
    #pragma unroll
    for (int r = 0; r < 4; ++r)
      bias[mi][r] = conv_b[g*512 + mt*256 + wr*128 + mi*16 + l4*4 + r];
  #pragma unroll
  for (int nj = 0; nj < 4; ++nj) {
    int n = nt*256 + wc*64 + nj*16 + l15;
    unsigned bb = (unsigned)n / 36u;
    unsigned pix = (unsigned)n % 36u;
    size_t base = ((size_t)g*B_ + bb)*FCK + (size_t)pix*512;
    #pragma unroll
    for (int mi = 0; mi < 8; ++mi) {
      int co0 = mt*256 + wr*128 + mi*16 + l4*4;
      u16 q[4];
      #pragma unroll
      for (int r = 0; r < 4; ++r)
        q[r] = f2bf(fmaxf(acc[mi][nj][r] + bias[mi][r], 0.f));
      *(short4v*)(feat + base + co0) = *(short4v*)q;
    }
  }
}

// ---------------- FC fused: per-group [128 x 18432] x f32 fc_w -> accum ----------------
// feat k-index is i' = pix*512 + co; B-stage gathers fc_w[g][co*36+pix][o]
// (8 rows at stride 5400 floats per thread, lanes = consecutive o -> 256B runs).
__global__ void __launch_bounds__(256) k_fc(const u16* __restrict__ feat,
                                            const float* __restrict__ fw,
                                            float* __restrict__ accum) {
  __shared__ __align__(16) u16 As[128*64];   // 16 KB
  __shared__ __align__(16) u16 Bs[160*64];   // 20 KB
  int sp = blockIdx.x;   // 0..31 k-split
  int g  = blockIdx.y;
  int tid = threadIdx.x;
  int lane = tid & 63, w = tid >> 6;
  int wr = w >> 1, wc = w & 1;
  int rl = lane >> 3, s = lane & 7;
  int l15 = lane & 15, l4 = lane >> 4;

  const u16* gA[4]; u16* lA[4];
  #pragma unroll
  for (int i = 0; i < 4; ++i) {
    int r = w*32 + i*8 + rl;
    int c = s ^ (r & 7);
    gA[i] = feat + ((size_t)g*B_ + r)*FCK + c*8;
    lA[i] = (u16*)As + (w*32 + i*8) * 64;
  }

  float4v acc[4][5];
  #pragma unroll
  for (int mi = 0; mi < 4; ++mi)
    #pragma unroll
    for (int nj = 0; nj < 5; ++nj) acc[mi][nj] = (float4v){0.f,0.f,0.f,0.f};

  int kbase = sp * 576;
  for (int stp = 0; stp < 9; ++stp) {
    int i0 = kbase + stp * 64;
    int pix = i0 >> 9;               // i0 / 512
    int cobase = i0 & 511;           // multiple of 64
    __syncthreads();
    #pragma unroll
    for (int i = 0; i < 4; ++i) load_lds16(gA[i] + i0, lA[i]);
    // ---- B stage: 1280 (il8, o) items over 5 iterations ----
    #pragma unroll
    for (int bit = 0; bit < 5; ++bit) {
      int idx = bit * 256 + tid;
      int il8 = idx / 160;           // k-slot 0..7
      int o   = idx - il8 * 160;     // 0..159
      u16 vals[8];
      if (o < 150) {
        const float* src = fw + ((size_t)g * FCK + (size_t)(cobase + il8 * 8) * 36 + pix) * 150 + o;
        #pragma unroll
        for (int j = 0; j < 8; ++j) vals[j] = f2bf(src[(size_t)j * 5400]);
      } else {
        #pragma unroll
        for (int j = 0; j < 8; ++j) vals[j] = 0;
      }
      *(short8*)((char*)Bs + o * 128 + ((il8 ^ (o & 7)) * 16)) = *(short8*)vals;
    }
    __syncthreads();

    short8 a[4][2], bf[5][2];
    #pragma unroll
    for (int kb = 0; kb < 2; ++kb) {
      #pragma unroll
      for (int mi = 0; mi < 4; ++mi) {
        int row = wr*64 + mi*16 + l15;
        int cb  = (kb*64 + l4*16) ^ ((row & 7) << 4);
        a[mi][kb] = *(const short8*)((const char*)As + row*128 + cb);
      }
      #pragma unroll
      for (int nj = 0; nj < 5; ++nj) {
        int row = wc*80 + nj*16 + l15;
        int cb  = (kb*64 + l4*16) ^ ((row & 7) << 4);
        bf[nj][kb] = *(const short8*)((const char*)Bs + row*128 + cb);
      }
    }
    #pragma unroll
    for (int kb = 0; kb < 2; ++kb)
      #pragma unroll
      for (int mi = 0; mi < 4; ++mi)
        #pragma unroll
        for (int nj = 0; nj < 5; ++nj)
          acc[mi][nj] = __builtin_amdgcn_mfma_f32_16x16x32_bf16(
              a[mi][kb], bf[nj][kb], acc[mi][nj], 0, 0, 0);
  }

  #pragma unroll
  for (int mi = 0; mi < 4; ++mi)
    #pragma unroll
    for (int r = 0; r < 4; ++r) {
      int brow = wr*64 + mi*16 + l4*4 + r;
      #pragma unroll
      for (int nj = 0; nj < 5; ++nj) {
        int o = wc*80 + nj*16 + l15;
        atomicAdd(&accum[((size_t)brow*20 + g)*160 + o], acc[mi][nj][r]);
      }
    }
}

__global__ void k_final(const float* __restrict__ accum, const float* __restrict__ fcb,
                        float* __restrict__ out) {
  int idx = blockIdx.x * 256 + threadIdx.x;     // 128*3000
  if (idx >= B_*3000) return;
  unsigned b = (unsigned)idx / 3000u;
  unsigned rem = (unsigned)idx % 3000u;
  unsigned g = rem / 150u, o = rem % 150u;
  out[idx] = fmaxf(accum[((size_t)b*20 + g)*160 + o] + fcb[g*150 + o], 0.f);
}

extern "C" void kernel_launch(void* const* d_in, const int* in_sizes, int n_in,
                              void* d_out, int out_size, void* d_ws, size_t ws_size,
                              hipStream_t stream) {
  const float* x      = (const float*)d_in[0];
  const float* y      = (const float*)d_in[1];
  const float* conv_w = (const float*)d_in[2];
  const float* conv_b = (const float*)d_in[3];
  const float* fc_w   = (const float*)d_in[4];
  const float* fc_b   = (const float*)d_in[5];
  float* out = (float*)d_out;

  char* ws = (char*)d_ws;
  size_t off = 0;
  u16* Wb   = (u16*)(ws + off); off += (size_t)10240 * K2 * 2;        // 94.4 MB
  u16* up3  = (u16*)(ws + off); off += (size_t)G_ * B_ * 64 * C_ * 2; // 167.8 MB
  u16* feat = (u16*)(ws + off); off += (size_t)G_ * B_ * FCK * 2;     // 94.4 MB
  float* accum = (float*)(ws + off); off += (size_t)B_ * G_ * 160 * 4;// 1.6 MB
  int* cx = (int*)(ws + off); off += B_ * G_ * 4;
  int* cy = (int*)(ws + off); off += B_ * G_ * 4;

  k_pos<<<1, 128, 0, stream>>>(y, cx, cy);
  hipMemsetAsync(accum, 0, (size_t)B_ * G_ * 160 * 4, stream);
  k_pre<<<5120, 256, 0, stream>>>(conv_w, Wb, x, cx, cy, up3);
  k_conv<<<720, 512, 0, stream>>>(Wb, up3, conv_b, feat);
  k_fc<<<dim3(32, 20), 256, 0, stream>>>(feat, fc_w, accum);
  k_final<<<(B_*3000 + 255)/256, 256, 0, stream>>>(accum, fc_b, out);
}